// Round 5
// baseline (714849.023 us; speedup 1.0000x reference)
//
#include <hip/hip_runtime.h>
#include <math.h>
#include <stdint.h>

// Problem constants
#define Bn 32
#define Sn 512
#define En 256
#define Hn 512
#define Ln 48
#define G4 2048        // 4*H
#define CLAIM_G 1024   // lstm_rec grid: WGs claim XCD-local team slots
#define SENT16 0x7FFFu // bf16 NaN — impossible for h = o*tanh(c), |h|<1

typedef unsigned short u16;
typedef __attribute__((ext_vector_type(8))) __bf16 bf16x8;
typedef __attribute__((ext_vector_type(4))) float f32x4;

__device__ inline float bf2f(u16 u) {
    return __uint_as_float(((unsigned)u) << 16);
}
__device__ inline u16 f2bf(float f) {
    unsigned u = __float_as_uint(f);
    unsigned r = (u + 0x7fffu + ((u >> 16) & 1u)) >> 16;  // RTNE
    return (u16)r;
}
__device__ inline float sigmoidf_(float x) { return 1.f / (1.f + expf(-x)); }
__device__ inline float tanh_fast(float x) { return 2.f / (1.f + expf(-2.f * x)) - 1.f; }

// any 16-bit field of the 4 dwords equals SENT16?
__device__ inline unsigned badMask(f32x4 v) {
    unsigned acc = 0;
    #pragma unroll
    for (int i = 0; i < 4; i++) {
        unsigned d = __float_as_uint(v[i]);
        unsigned x = d ^ 0x7FFF7FFFu;
        acc |= (x - 0x00010001u) & ~x & 0x80008000u;
    }
    return acc;
}

// ---------------------------------------------------------------------------
// prep: embed gather -> bf16 x, weight bf16 conversions, exp(T), zero accums,
// sentinel-fill h buffers, zero claim + flag state
// ---------------------------------------------------------------------------
__global__ __launch_bounds__(256) void prep_kernel(
    const int* __restrict__ tokens, const float* __restrict__ embed,
    const float* __restrict__ wihf, const float* __restrict__ wihb,
    const float* __restrict__ whhf, const float* __restrict__ whhb,
    const float* __restrict__ wem, const float* __restrict__ trans,
    u16* __restrict__ xbf, u16* __restrict__ wihf_b, u16* __restrict__ wihb_b,
    u16* __restrict__ whhf_b, u16* __restrict__ whhb_b, u16* __restrict__ wem_b,
    float* __restrict__ expT, float* __restrict__ alphaAcc,
    float* __restrict__ realAcc, unsigned* __restrict__ hf32,
    unsigned* __restrict__ hb32, int* __restrict__ claimCnt,
    int* __restrict__ teamCnt, int* __restrict__ teamRole,
    int* __restrict__ flags)
{
    size_t idx = (size_t)blockIdx.x * blockDim.x + threadIdx.x;
    size_t stride = (size_t)gridDim.x * blockDim.x;
    for (size_t i = idx; i < (size_t)Bn * Sn * En; i += stride) {
        size_t n = i >> 8; int ee = (int)(i & 255);
        int tok = tokens[n];
        xbf[i] = f2bf(embed[(size_t)tok * En + ee]);
    }
    for (size_t i = idx; i < (size_t)G4 * En; i += stride) {
        wihf_b[i] = f2bf(wihf[i]); wihb_b[i] = f2bf(wihb[i]);
    }
    for (size_t i = idx; i < (size_t)G4 * Hn; i += stride) {
        whhf_b[i] = f2bf(whhf[i]); whhb_b[i] = f2bf(whhb[i]);
    }
    for (size_t i = idx; i < (size_t)Ln * 2 * Hn; i += stride) wem_b[i] = f2bf(wem[i]);
    for (size_t i = idx; i < (size_t)Ln * Ln; i += stride) expT[i] = expf(trans[i]);
    for (size_t i = idx; i < (size_t)Bn * Ln; i += stride) alphaAcc[i] = 0.f;
    for (size_t i = idx; i < (size_t)Bn; i += stride) realAcc[i] = 0.f;
    for (size_t i = idx; i < 16; i += stride) { claimCnt[i] = 0; teamRole[i] = 0; }
    for (size_t i = idx; i < 1; i += stride) teamCnt[0] = 0;
    for (size_t i = idx; i < (size_t)2 * Sn * 32; i += stride) flags[i] = 0;
    const unsigned sp = (SENT16 << 16) | SENT16;
    for (size_t i = idx; i < (size_t)Bn * Sn * Hn / 2; i += stride) {
        hf32[i] = sp; hb32[i] = sp;
    }
}

// ---------------------------------------------------------------------------
// gemm_xw: xw[dir][t][b][g] = x(b,t) . w_ih[g] + bias[g], bf16 MFMA, fp32 acc
// ---------------------------------------------------------------------------
__global__ __launch_bounds__(256) void gemm_xw(
    const u16* __restrict__ xbf, const u16* __restrict__ wihf_b,
    const u16* __restrict__ wihb_b, const float* __restrict__ bias_f,
    const float* __restrict__ bias_b, u16* __restrict__ xw_f, u16* __restrict__ xw_b)
{
    int mb = blockIdx.x, nb = blockIdx.y, dir = blockIdx.z;
    const u16* wih = dir ? wihb_b : wihf_b;
    const float* bias = dir ? bias_b : bias_f;
    u16* xw = dir ? xw_b : xw_f;

    __shared__ u16 As[128 * 72];   // 128 rows x 64 k, pad 8
    __shared__ u16 Bs[128 * 72];

    int tid = threadIdx.x;
    int w = tid >> 6, lane = tid & 63;
    int lm = lane & 15, kq = lane >> 4;
    int Moff = (w & 1) * 64, Noff = (w >> 1) * 64;

    f32x4 zero = {0.f, 0.f, 0.f, 0.f};
    f32x4 acc[4][4];
    #pragma unroll
    for (int mi = 0; mi < 4; mi++)
        #pragma unroll
        for (int ni = 0; ni < 4; ni++) acc[mi][ni] = zero;

    for (int kc = 0; kc < 4; kc++) {
        #pragma unroll
        for (int it = 0; it < 4; it++) {
            int idx = tid + it * 256;
            int r = idx >> 3, pos = (idx & 7) * 8;
            *(bf16x8*)&As[r * 72 + pos] =
                *(const bf16x8*)&xbf[((size_t)(mb * 128 + r)) * En + kc * 64 + pos];
            *(bf16x8*)&Bs[r * 72 + pos] =
                *(const bf16x8*)&wih[((size_t)(nb * 128 + r)) * En + kc * 64 + pos];
        }
        __syncthreads();
        #pragma unroll
        for (int ks = 0; ks < 2; ks++) {
            int k = ks * 32 + kq * 8;
            bf16x8 af[4], bfr[4];
            #pragma unroll
            for (int mi = 0; mi < 4; mi++)
                af[mi] = *(const bf16x8*)&As[(Moff + mi * 16 + lm) * 72 + k];
            #pragma unroll
            for (int ni = 0; ni < 4; ni++)
                bfr[ni] = *(const bf16x8*)&Bs[(Noff + ni * 16 + lm) * 72 + k];
            #pragma unroll
            for (int mi = 0; mi < 4; mi++)
                #pragma unroll
                for (int ni = 0; ni < 4; ni++)
                    acc[mi][ni] = __builtin_amdgcn_mfma_f32_16x16x32_bf16(
                        af[mi], bfr[ni], acc[mi][ni], 0, 0, 0);
        }
        __syncthreads();
    }
    #pragma unroll
    for (int mi = 0; mi < 4; mi++)
        #pragma unroll
        for (int ni = 0; ni < 4; ni++)
            #pragma unroll
            for (int reg = 0; reg < 4; reg++) {
                int row = Moff + mi * 16 + kq * 4 + reg;
                int col = Noff + ni * 16 + lm;
                int n = mb * 128 + row;          // n = b*512 + t
                int g = nb * 128 + col;
                int t = n & 511, b = n >> 9;
                float v = acc[mi][ni][reg] + bias[g];
                xw[((size_t)t * Bn + b) * G4 + g] = f2bf(v);
            }
}

// ---------------------------------------------------------------------------
// lstm_rec (R13): 1024 plain WGs x 512 thr. R12's proven XCD-local claiming
// (teams of 32 WGs, each fully on one XCD). Exchange protocol changed from
// sentinel data-polling (32KB/WG/round -> L2 storm, R12's 3.6x regression)
// to FLAG-based readiness:
//   producer wave 0: store h slice sc0; s_waitcnt vmcnt(0); lane0 stores
//     flags[dir][t][w]=1 sc0  (store-complete = L2-visible on this XCD).
//   consumer: each wave polls flags[dir][tprev][lane&31] (4B sc0, bypasses
//     L1) until ballot-full, then loads the h row ONCE (sc0).
// Poll traffic 16x lower; data read exactly once. Backstops: data is still
// sentinel-checked once (fallback = R8-proven bounded sc1 retry loop); flag
// poll bounded -> never hangs. Single sc0 h store (kernel-end flush covers
// emis_crf visibility).
// ---------------------------------------------------------------------------
__global__ __launch_bounds__(512) void lstm_rec(
    const u16* __restrict__ whhf_b, const u16* __restrict__ whhb_b,
    const u16* __restrict__ xw_f, const u16* __restrict__ xw_b,
    u16* __restrict__ hf, u16* __restrict__ hb,
    int* __restrict__ claimCnt, int* __restrict__ teamCnt,
    int* __restrict__ teamRole, int* __restrict__ flags)
{
    __shared__ int roleS[2];
    int tid = threadIdx.x;

    if (tid == 0) {
        unsigned xcdr;
        asm volatile("s_getreg_b32 %0, hwreg(HW_REG_XCC_ID)" : "=s"(xcdr));
        int myx = (int)(xcdr & 15);
        int slot = __hip_atomic_fetch_add(&claimCnt[myx], 1,
                                          __ATOMIC_ACQ_REL, __HIP_MEMORY_SCOPE_AGENT);
        int dir = -1;
        if (slot < 32) {
            if (slot == 31) {
                int ticket = __hip_atomic_fetch_add(teamCnt, 1,
                                  __ATOMIC_ACQ_REL, __HIP_MEMORY_SCOPE_AGENT);
                int role = (ticket == 0) ? 1 : (ticket == 1) ? 2 : -1;
                __hip_atomic_store(&teamRole[myx], role,
                                   __ATOMIC_RELEASE, __HIP_MEMORY_SCOPE_AGENT);
                dir = (role > 0) ? role - 1 : -1;
            } else {
                int r = 0, guard = 0;
                for (;;) {
                    r = __hip_atomic_load(&teamRole[myx],
                                          __ATOMIC_ACQUIRE, __HIP_MEMORY_SCOPE_AGENT);
                    if (r != 0) break;
                    if (++guard > (1 << 22)) break;   // failsafe
                    __builtin_amdgcn_s_sleep(2);
                }
                dir = (r > 0) ? r - 1 : -1;
            }
        }
        roleS[0] = dir;
        roleS[1] = slot & 31;
    }
    __syncthreads();
    int dir = roleS[0];
    int w = roleS[1];
    if (dir < 0) return;

    const u16* __restrict__ whh = dir ? whhb_b : whhf_b;
    const u16* __restrict__ xw  = dir ? xw_b  : xw_f;
    u16* __restrict__ hbuf = dir ? hb : hf;
    int* __restrict__ myflags = &flags[(size_t)dir * Sn * 32];

    __shared__ u16 Hs[32 * 512];        // h_{t-1} staged, XOR-swizzled chunks
    __shared__ float Cp[4 * 32 * 17];   // gate partials [gate][batch][hcol]
    __shared__ u16 hout[32 * 16];

    int wv = tid >> 6, lane = tid & 63;
    int lm = lane & 15, kq = lane >> 4;
    int mt = wv & 1, nt = wv >> 1;       // wave -> (batch-tile, gate)
    int b = tid >> 4, hc = tid & 15;     // gate-phase / staging role

    // B fragments (w_hh rows for gate nt, hidden cols w*16..+16) in registers
    bf16x8 Bf[16];
    {
        const u16* wrow = &whh[((size_t)nt * Hn + (size_t)w * 16 + lm) * Hn];
        #pragma unroll
        for (int ks = 0; ks < 16; ks++)
            Bf[ks] = *(const bf16x8*)&wrow[ks * 32 + kq * 8];
    }

    float c_state = 0.f;
    const f32x4 zero = {0.f, 0.f, 0.f, 0.f};

    for (int it = 0; it < Sn; it++) {
        int t = dir ? (Sn - 1 - it) : it;
        f32x4 acc = zero;

        // xw gate inputs for (b, hc) — independent of h; issue before the wait
        const u16* xp = &xw[((size_t)t * Bn + b) * G4 + (size_t)w * 16 + hc];
        float xg0 = bf2f(xp[0 * Hn]);
        float xg1 = bf2f(xp[1 * Hn]);
        float xg2 = bf2f(xp[2 * Hn]);
        float xg3 = bf2f(xp[3 * Hn]);

        if (it > 0) {
            int tprev = dir ? (t + 1) : (t - 1);
            // -------- flag wait: 4B/lane poll, sc0 (bypasses L1) --------
            const int* fp = &myflags[(size_t)tprev * 32 + (lane & 31)];
            int rounds = 0;
            bool fellback = false;
            for (;;) {
                int fv;
                asm volatile(
                    "global_load_dword %0, %1, off sc0\n\t"
                    "s_waitcnt vmcnt(0)"
                    : "=v"(fv) : "v"(fp) : "memory");
                if (__ballot(fv != 0) == ~0ull) break;
                if (++rounds > (1 << 14)) { fellback = true; break; }
                __builtin_amdgcn_s_sleep(1);
            }
            // -------- single-shot data load (sc0, served by local L2) ----
            const u16* base = &hbuf[((size_t)b * Sn + tprev) * Hn];
            const u16* p0 = base + (hc + 0) * 8;
            const u16* p1 = base + (hc + 16) * 8;
            const u16* p2 = base + (hc + 32) * 8;
            const u16* p3 = base + (hc + 48) * 8;
            f32x4 h0, h1, h2, h3;
            asm volatile(
                "global_load_dwordx4 %0, %4, off sc0\n\t"
                "global_load_dwordx4 %1, %5, off sc0\n\t"
                "global_load_dwordx4 %2, %6, off sc0\n\t"
                "global_load_dwordx4 %3, %7, off sc0\n\t"
                "s_waitcnt vmcnt(0)"
                : "=&v"(h0), "=&v"(h1), "=&v"(h2), "=&v"(h3)
                : "v"(p0), "v"(p1), "v"(p2), "v"(p3)
                : "memory");
            // -------- backstop: sentinel check + R8-proven sc1 retry -----
            if (fellback | (badMask(h0) | badMask(h1) | badMask(h2) | badMask(h3))) {
                int tries = 0;
                for (;;) {
                    asm volatile(
                        "global_load_dwordx4 %0, %4, off sc1\n\t"
                        "global_load_dwordx4 %1, %5, off sc1\n\t"
                        "global_load_dwordx4 %2, %6, off sc1\n\t"
                        "global_load_dwordx4 %3, %7, off sc1\n\t"
                        "s_waitcnt vmcnt(0)"
                        : "=&v"(h0), "=&v"(h1), "=&v"(h2), "=&v"(h3)
                        : "v"(p0), "v"(p1), "v"(p2), "v"(p3)
                        : "memory");
                    if (!(badMask(h0) | badMask(h1) | badMask(h2) | badMask(h3))) break;
                    if (++tries > (1 << 16)) break;   // fail-safe: never hang
                }
            }
            *(f32x4*)&Hs[(b * 64 + ((hc + 0) ^ (b & 7))) * 8] = h0;
            *(f32x4*)&Hs[(b * 64 + ((hc + 16) ^ (b & 7))) * 8] = h1;
            *(f32x4*)&Hs[(b * 64 + ((hc + 32) ^ (b & 7))) * 8] = h2;
            *(f32x4*)&Hs[(b * 64 + ((hc + 48) ^ (b & 7))) * 8] = h3;
            __syncthreads();                              // sync #1

            f32x4 aa = zero, ab = zero;
            #pragma unroll
            for (int ks2 = 0; ks2 < 8; ks2++) {
                bf16x8 a0 = *(const bf16x8*)
                    &Hs[((mt * 16 + lm) * 64 + (((2 * ks2) * 4 + kq) ^ (lm & 7))) * 8];
                aa = __builtin_amdgcn_mfma_f32_16x16x32_bf16(a0, Bf[2 * ks2], aa, 0, 0, 0);
                bf16x8 a1 = *(const bf16x8*)
                    &Hs[((mt * 16 + lm) * 64 + (((2 * ks2 + 1) * 4 + kq) ^ (lm & 7))) * 8];
                ab = __builtin_amdgcn_mfma_f32_16x16x32_bf16(a1, Bf[2 * ks2 + 1], ab, 0, 0, 0);
            }
            acc = aa + ab;
        }

        #pragma unroll
        for (int reg = 0; reg < 4; reg++)
            Cp[(nt * 32 + mt * 16 + kq * 4 + reg) * 17 + lm] = acc[reg];
        __syncthreads();                                  // sync #2

        float g0 = Cp[(0 * 32 + b) * 17 + hc] + xg0;
        float g1 = Cp[(1 * 32 + b) * 17 + hc] + xg1;
        float g2 = Cp[(2 * 32 + b) * 17 + hc] + xg2;
        float g3 = Cp[(3 * 32 + b) * 17 + hc] + xg3;
        float i_ = sigmoidf_(g0);
        float f_ = sigmoidf_(g1);
        float gg = tanh_fast(g2);
        float o_ = sigmoidf_(g3);
        c_state = f_ * c_state + i_ * gg;
        float hv = o_ * tanh_fast(c_state);
        hout[tid] = f2bf(hv);
        __syncthreads();                                  // sync #3

        if (tid < 64) {
            int bq = lane >> 1, half = lane & 1;
            f32x4 hv8 = *(const f32x4*)&hout[lane * 8];
            u16* sp = &hbuf[((size_t)bq * Sn + t) * Hn + (size_t)w * 16 + half * 8];
            // h slice: single sc0 store (local L2 = visibility point for team)
            asm volatile("global_store_dwordx4 %0, %1, off sc0"
                         :: "v"(sp), "v"(hv8) : "memory");
            // release: wait own stores committed, then set this column's flag
            asm volatile("s_waitcnt vmcnt(0)" ::: "memory");
            if (lane == 0) {
                int one = 1;
                int* fstp = &myflags[(size_t)t * 32 + w];
                asm volatile("global_store_dword %0, %1, off sc0"
                             :: "v"(fstp), "v"(one) : "memory");
            }
        }
    }
}

// ---------------------------------------------------------------------------
// emis_crf: fused emission GEMM + exp + CRF accumulation.
// ---------------------------------------------------------------------------
__global__ __launch_bounds__(256) void emis_crf(
    const u16* __restrict__ hf, const u16* __restrict__ hb,
    const u16* __restrict__ wem_b, const float* __restrict__ bem,
    const float* __restrict__ expT, const int* __restrict__ labels,
    const int* __restrict__ lengths, float* __restrict__ e0,
    float* __restrict__ alphaAcc, float* __restrict__ realAcc)
{
    int mb = blockIdx.x;                 // 256 blocks
    int b = mb >> 3, t0 = (mb & 7) * 64; // rows mb*64.. are (b, t0..t0+64)

    __shared__ float eL[64][49];
    __shared__ float Ts[48 * 48];
    __shared__ float sred[4][48];
    __shared__ float rred[64];

    int tid = threadIdx.x;
    for (int i = tid; i < 48 * 48; i += 256) Ts[i] = expT[i];

    int wv = tid >> 6, lane = tid & 63;
    int lm = lane & 15, lkq = (lane >> 4) * 8;
    int row = mb * 64 + wv * 16;

    f32x4 zero = {0.f, 0.f, 0.f, 0.f};
    f32x4 acc[3] = {zero, zero, zero};
    for (int ks = 0; ks < 32; ks++) {
        int k = ks * 32 + lkq;
        const u16* hsrc = (ks < 16) ? &hf[(size_t)(row + lm) * Hn + k]
                                    : &hb[(size_t)(row + lm) * Hn + (k - 512)];
        bf16x8 a = *(const bf16x8*)hsrc;
        #pragma unroll
        for (int nt = 0; nt < 3; nt++) {
            bf16x8 bfr = *(const bf16x8*)&wem_b[(size_t)(nt * 16 + lm) * 1024 + k];
            acc[nt] = __builtin_amdgcn_mfma_f32_16x16x32_bf16(a, bfr, acc[nt], 0, 0, 0);
        }
    }
    #pragma unroll
    for (int nt = 0; nt < 3; nt++)
        #pragma unroll
        for (int reg = 0; reg < 4; reg++) {
            int rib = wv * 16 + (lane >> 4) * 4 + reg;   // row in block = t - t0
            int col = nt * 16 + lm;
            float v = expf(acc[nt][reg] + bem[col]);
            eL[rib][col] = v;
            if ((mb & 7) == 0 && rib == 0) e0[b * Ln + col] = v;   // t == 0
        }
    __syncthreads();

    int len = lengths[b];
    if (tid < 192) {
        int i = tid % 48, tg = tid / 48;   // 4 groups x 48 labels
        float sacc = 0.f;
        for (int p = tg * 16; p < tg * 16 + 16; p++) {
            int t = t0 + p;
            if (t >= 1 && t < len) {
                float m = -1e30f;
                for (int j = 0; j < 48; j++) m = fmaxf(m, Ts[i * 48 + j] + eL[p][j]);
                float s = 0.f;
                for (int j = 0; j < 48; j++) s += expf(Ts[i * 48 + j] + eL[p][j] - m);
                sacc += m + logf(s);
            }
        }
        sred[tg][i] = sacc;
    } else {
        int p = tid - 192;                  // 0..63
        int t = t0 + p;
        float r = 0.f;
        if (t < len) {
            int lab = labels[b * Sn + t];
            r = eL[p][lab];
            if (t >= 1) r += Ts[labels[b * Sn + t - 1] * 48 + lab];
        }
        rred[p] = r;
    }
    __syncthreads();
    if (tid < 48) {
        float s = sred[0][tid] + sred[1][tid] + sred[2][tid] + sred[3][tid];
        atomicAdd(&alphaAcc[b * Ln + tid], s);
    } else if (tid == 48) {
        float r = 0.f;
        for (int p = 0; p < 64; p++) r += rred[p];
        atomicAdd(&realAcc[b], r);
    }
}

__global__ __launch_bounds__(64) void finalize(
    const float* __restrict__ e0, const float* __restrict__ alphaAcc,
    const float* __restrict__ realAcc, float* __restrict__ out)
{
    int b = threadIdx.x;
    if (b >= Bn) return;
    float m = -1e30f;
    for (int i = 0; i < Ln; i++) {
        float a = e0[b * Ln + i] + alphaAcc[b * Ln + i];
        m = fmaxf(m, a);
    }
    float s = 0.f;
    for (int i = 0; i < Ln; i++) {
        float a = e0[b * Ln + i] + alphaAcc[b * Ln + i];
        s += expf(a - m);
    }
    out[b] = m + logf(s) - realAcc[b];
}

// ---------------------------------------------------------------------------
extern "C" void kernel_launch(void* const* d_in, const int* in_sizes, int n_in,
                              void* d_out, int out_size, void* d_ws, size_t ws_size,
                              hipStream_t stream)
{
    const int*   tokens = (const int*)d_in[0];
    const int*   length = (const int*)d_in[1];
    const int*   labels = (const int*)d_in[2];
    const float* embed  = (const float*)d_in[3];
    const float* wihf   = (const float*)d_in[4];
    const float* whhf   = (const float*)d_in[5];
    const float* bf     = (const float*)d_in[6];
    const float* wihb   = (const float*)d_in[7];
    const float* whhb   = (const float*)d_in[8];
    const float* bbv    = (const float*)d_in[9];
    const float* wem    = (const float*)d_in[10];
    const float* bem    = (const float*)d_in[11];
    const float* trans  = (const float*)d_in[12];
    float* out = (float*)d_out;

    char* p = (char*)d_ws;
    auto take = [&](size_t bytes) -> char* {
        char* q = p;
        p += (bytes + 255) & ~(size_t)255;
        return q;
    };
    u16* xw_f   = (u16*)take((size_t)Sn * Bn * G4 * 2);   // 64 MB
    u16* xw_b   = (u16*)take((size_t)Sn * Bn * G4 * 2);   // 64 MB
    u16* hf     = (u16*)take((size_t)Bn * Sn * Hn * 2);   // 16 MB, layout [b][t][k]
    u16* hb     = (u16*)take((size_t)Bn * Sn * Hn * 2);   // 16 MB, layout [b][t][k]
    u16* xbf    = (u16*)take((size_t)Bn * Sn * En * 2);   // 8 MB
    u16* wihf_b = (u16*)take((size_t)G4 * En * 2);
    u16* wihb_b = (u16*)take((size_t)G4 * En * 2);
    u16* whhf_b = (u16*)take((size_t)G4 * Hn * 2);
    u16* whhb_b = (u16*)take((size_t)G4 * Hn * 2);
    u16* wem_b  = (u16*)take((size_t)Ln * 2 * Hn * 2);
    float* expT     = (float*)take((size_t)Ln * Ln * 4);
    float* e0       = (float*)take((size_t)Bn * Ln * 4);
    float* alphaAcc = (float*)take((size_t)Bn * Ln * 4);
    float* realAcc  = (float*)take((size_t)Bn * 4);
    int* claimCnt   = (int*)take(16 * 4);
    int* teamCnt    = (int*)take(4);
    int* teamRole   = (int*)take(16 * 4);
    int* flags      = (int*)take((size_t)2 * Sn * 32 * 4);   // 128 KB
    if ((size_t)(p - (char*)d_ws) > ws_size) return;

    prep_kernel<<<4096, 256, 0, stream>>>(tokens, embed, wihf, wihb, whhf, whhb, wem, trans,
                                          xbf, wihf_b, wihb_b, whhf_b, whhb_b, wem_b,
                                          expT, alphaAcc, realAcc,
                                          (unsigned*)hf, (unsigned*)hb,
                                          claimCnt, teamCnt, teamRole, flags);

    dim3 g1(128, 16, 2);
    gemm_xw<<<g1, 256, 0, stream>>>(xbf, wihf_b, wihb_b, bf, bbv, xw_f, xw_b);

    lstm_rec<<<CLAIM_G, 512, 0, stream>>>(whhf_b, whhb_b, xw_f, xw_b, hf, hb,
                                          claimCnt, teamCnt, teamRole, flags);

    emis_crf<<<256, 256, 0, stream>>>(hf, hb, wem_b, bem, expT, labels, length,
                                      e0, alphaAcc, realAcc);
    finalize<<<1, 64, 0, stream>>>(e0, alphaAcc, realAcc, out);
}

// Round 7
// 3428.176 us; speedup vs baseline: 208.5217x; 208.5217x over previous
//
#include <hip/hip_runtime.h>
#include <math.h>
#include <stdint.h>

// Problem constants
#define Bn 32
#define Sn 512
#define En 256
#define Hn 512
#define Ln 48
#define G4 2048        // 4*H
#define CLAIM_G 1024   // lstm_rec grid: WGs claim XCD-local team slots
#define SENT16 0x7FFFu // bf16 NaN — impossible for h = o*tanh(c), |h|<1

typedef unsigned short u16;
typedef __attribute__((ext_vector_type(8))) __bf16 bf16x8;
typedef __attribute__((ext_vector_type(4))) float f32x4;

__device__ inline float bf2f(u16 u) {
    return __uint_as_float(((unsigned)u) << 16);
}
__device__ inline u16 f2bf(float f) {
    unsigned u = __float_as_uint(f);
    unsigned r = (u + 0x7fffu + ((u >> 16) & 1u)) >> 16;  // RTNE
    return (u16)r;
}
__device__ inline float sigmoidf_(float x) { return 1.f / (1.f + expf(-x)); }
__device__ inline float tanh_fast(float x) { return 2.f / (1.f + expf(-2.f * x)) - 1.f; }

// any 16-bit field of the 4 dwords equals SENT16?
__device__ inline unsigned badMask(f32x4 v) {
    unsigned acc = 0;
    #pragma unroll
    for (int i = 0; i < 4; i++) {
        unsigned d = __float_as_uint(v[i]);
        unsigned x = d ^ 0x7FFF7FFFu;
        acc |= (x - 0x00010001u) & ~x & 0x80008000u;
    }
    return acc;
}

// ---------------------------------------------------------------------------
// prep: embed gather -> bf16 x, weight bf16 conversions, exp(T), zero accums,
// sentinel-fill h buffers, zero claim state
// ---------------------------------------------------------------------------
__global__ __launch_bounds__(256) void prep_kernel(
    const int* __restrict__ tokens, const float* __restrict__ embed,
    const float* __restrict__ wihf, const float* __restrict__ wihb,
    const float* __restrict__ whhf, const float* __restrict__ whhb,
    const float* __restrict__ wem, const float* __restrict__ trans,
    u16* __restrict__ xbf, u16* __restrict__ wihf_b, u16* __restrict__ wihb_b,
    u16* __restrict__ whhf_b, u16* __restrict__ whhb_b, u16* __restrict__ wem_b,
    float* __restrict__ expT, float* __restrict__ alphaAcc,
    float* __restrict__ realAcc, unsigned* __restrict__ hf32,
    unsigned* __restrict__ hb32, int* __restrict__ claimCnt,
    int* __restrict__ teamCnt, int* __restrict__ teamRole)
{
    size_t idx = (size_t)blockIdx.x * blockDim.x + threadIdx.x;
    size_t stride = (size_t)gridDim.x * blockDim.x;
    for (size_t i = idx; i < (size_t)Bn * Sn * En; i += stride) {
        size_t n = i >> 8; int ee = (int)(i & 255);
        int tok = tokens[n];
        xbf[i] = f2bf(embed[(size_t)tok * En + ee]);
    }
    for (size_t i = idx; i < (size_t)G4 * En; i += stride) {
        wihf_b[i] = f2bf(wihf[i]); wihb_b[i] = f2bf(wihb[i]);
    }
    for (size_t i = idx; i < (size_t)G4 * Hn; i += stride) {
        whhf_b[i] = f2bf(whhf[i]); whhb_b[i] = f2bf(whhb[i]);
    }
    for (size_t i = idx; i < (size_t)Ln * 2 * Hn; i += stride) wem_b[i] = f2bf(wem[i]);
    for (size_t i = idx; i < (size_t)Ln * Ln; i += stride) expT[i] = expf(trans[i]);
    for (size_t i = idx; i < (size_t)Bn * Ln; i += stride) alphaAcc[i] = 0.f;
    for (size_t i = idx; i < (size_t)Bn; i += stride) realAcc[i] = 0.f;
    for (size_t i = idx; i < 16; i += stride) { claimCnt[i] = 0; teamRole[i] = 0; }
    for (size_t i = idx; i < 1; i += stride) teamCnt[0] = 0;
    const unsigned sp = (SENT16 << 16) | SENT16;
    for (size_t i = idx; i < (size_t)Bn * Sn * Hn / 2; i += stride) {
        hf32[i] = sp; hb32[i] = sp;
    }
}

// ---------------------------------------------------------------------------
// gemm_xw: xw[dir][t][b][g] = x(b,t) . w_ih[g] + bias[g], bf16 MFMA, fp32 acc
// ---------------------------------------------------------------------------
__global__ __launch_bounds__(256) void gemm_xw(
    const u16* __restrict__ xbf, const u16* __restrict__ wihf_b,
    const u16* __restrict__ wihb_b, const float* __restrict__ bias_f,
    const float* __restrict__ bias_b, u16* __restrict__ xw_f, u16* __restrict__ xw_b)
{
    int mb = blockIdx.x, nb = blockIdx.y, dir = blockIdx.z;
    const u16* wih = dir ? wihb_b : wihf_b;
    const float* bias = dir ? bias_b : bias_f;
    u16* xw = dir ? xw_b : xw_f;

    __shared__ u16 As[128 * 72];   // 128 rows x 64 k, pad 8
    __shared__ u16 Bs[128 * 72];

    int tid = threadIdx.x;
    int w = tid >> 6, lane = tid & 63;
    int lm = lane & 15, kq = lane >> 4;
    int Moff = (w & 1) * 64, Noff = (w >> 1) * 64;

    f32x4 zero = {0.f, 0.f, 0.f, 0.f};
    f32x4 acc[4][4];
    #pragma unroll
    for (int mi = 0; mi < 4; mi++)
        #pragma unroll
        for (int ni = 0; ni < 4; ni++) acc[mi][ni] = zero;

    for (int kc = 0; kc < 4; kc++) {
        #pragma unroll
        for (int it = 0; it < 4; it++) {
            int idx = tid + it * 256;
            int r = idx >> 3, pos = (idx & 7) * 8;
            *(bf16x8*)&As[r * 72 + pos] =
                *(const bf16x8*)&xbf[((size_t)(mb * 128 + r)) * En + kc * 64 + pos];
            *(bf16x8*)&Bs[r * 72 + pos] =
                *(const bf16x8*)&wih[((size_t)(nb * 128 + r)) * En + kc * 64 + pos];
        }
        __syncthreads();
        #pragma unroll
        for (int ks = 0; ks < 2; ks++) {
            int k = ks * 32 + kq * 8;
            bf16x8 af[4], bfr[4];
            #pragma unroll
            for (int mi = 0; mi < 4; mi++)
                af[mi] = *(const bf16x8*)&As[(Moff + mi * 16 + lm) * 72 + k];
            #pragma unroll
            for (int ni = 0; ni < 4; ni++)
                bfr[ni] = *(const bf16x8*)&Bs[(Noff + ni * 16 + lm) * 72 + k];
            #pragma unroll
            for (int mi = 0; mi < 4; mi++)
                #pragma unroll
                for (int ni = 0; ni < 4; ni++)
                    acc[mi][ni] = __builtin_amdgcn_mfma_f32_16x16x32_bf16(
                        af[mi], bfr[ni], acc[mi][ni], 0, 0, 0);
        }
        __syncthreads();
    }
    #pragma unroll
    for (int mi = 0; mi < 4; mi++)
        #pragma unroll
        for (int ni = 0; ni < 4; ni++)
            #pragma unroll
            for (int reg = 0; reg < 4; reg++) {
                int row = Moff + mi * 16 + kq * 4 + reg;
                int col = Noff + ni * 16 + lm;
                int n = mb * 128 + row;          // n = b*512 + t
                int g = nb * 128 + col;
                int t = n & 511, b = n >> 9;
                float v = acc[mi][ni][reg] + bias[g];
                xw[((size_t)t * Bn + b) * G4 + g] = f2bf(v);
            }
}

// ---------------------------------------------------------------------------
// lstm_rec (R15): 1024 plain WGs x 512 thr. R12's PROVEN XCD-local claiming
// (2 teams of 32 WGs, each fully on one XCD; non-members exit). Exchange:
//   producer: dual store — sc0 (XCD-local L2 copy) + sc0 sc1 (MALL backstop)
//   consumer: R8's PROVEN single-asm sc1 sentinel poll. sc1 loads bypass L1
//     (stale-proof, proven by R8); for a same-XCD producer the local L2 must
//     service its dirty line -> ~0.3us RTT instead of MALL's ~2.5us. If sc1
//     routes to MALL anyway, the backstop copy serves it at R8 speed — the
//     experiment is downside-bounded to baseline behavior.
// All loops bounded; teams proven to form (R12/R13); claiming state re-zeroed
// by prep each launch.
// ---------------------------------------------------------------------------
__global__ __launch_bounds__(512) void lstm_rec(
    const u16* __restrict__ whhf_b, const u16* __restrict__ whhb_b,
    const u16* __restrict__ xw_f, const u16* __restrict__ xw_b,
    u16* __restrict__ hf, u16* __restrict__ hb,
    int* __restrict__ claimCnt, int* __restrict__ teamCnt,
    int* __restrict__ teamRole)
{
    __shared__ int roleS[2];
    int tid = threadIdx.x;

    if (tid == 0) {
        unsigned xcdr;
        asm volatile("s_getreg_b32 %0, hwreg(HW_REG_XCC_ID)" : "=s"(xcdr));
        int myx = (int)(xcdr & 15);
        int slot = __hip_atomic_fetch_add(&claimCnt[myx], 1,
                                          __ATOMIC_ACQ_REL, __HIP_MEMORY_SCOPE_AGENT);
        int dir = -1;
        if (slot < 32) {
            if (slot == 31) {
                int ticket = __hip_atomic_fetch_add(teamCnt, 1,
                                  __ATOMIC_ACQ_REL, __HIP_MEMORY_SCOPE_AGENT);
                int role = (ticket == 0) ? 1 : (ticket == 1) ? 2 : -1;
                __hip_atomic_store(&teamRole[myx], role,
                                   __ATOMIC_RELEASE, __HIP_MEMORY_SCOPE_AGENT);
                dir = (role > 0) ? role - 1 : -1;
            } else {
                int r = 0, guard = 0;
                for (;;) {
                    r = __hip_atomic_load(&teamRole[myx],
                                          __ATOMIC_ACQUIRE, __HIP_MEMORY_SCOPE_AGENT);
                    if (r != 0) break;
                    if (++guard > (1 << 22)) break;   // failsafe
                    __builtin_amdgcn_s_sleep(2);
                }
                dir = (r > 0) ? r - 1 : -1;
            }
        }
        roleS[0] = dir;
        roleS[1] = slot & 31;
    }
    __syncthreads();
    int dir = roleS[0];
    int w = roleS[1];
    if (dir < 0) return;

    const u16* __restrict__ whh = dir ? whhb_b : whhf_b;
    const u16* __restrict__ xw  = dir ? xw_b  : xw_f;
    u16* __restrict__ hbuf = dir ? hb : hf;

    __shared__ u16 Hs[32 * 512];        // h_{t-1} staged, XOR-swizzled chunks
    __shared__ float Cp[4 * 32 * 17];   // gate partials [gate][batch][hcol]
    __shared__ u16 hout[32 * 16];

    int wv = tid >> 6, lane = tid & 63;
    int lm = lane & 15, kq = lane >> 4;
    int mt = wv & 1, nt = wv >> 1;       // wave -> (batch-tile, gate)
    int b = tid >> 4, hc = tid & 15;     // gate-phase / staging role

    // B fragments (w_hh rows for gate nt, hidden cols w*16..+16) in registers
    bf16x8 Bf[16];
    {
        const u16* wrow = &whh[((size_t)nt * Hn + (size_t)w * 16 + lm) * Hn];
        #pragma unroll
        for (int ks = 0; ks < 16; ks++)
            Bf[ks] = *(const bf16x8*)&wrow[ks * 32 + kq * 8];
    }

    float c_state = 0.f;
    const f32x4 zero = {0.f, 0.f, 0.f, 0.f};

    for (int it = 0; it < Sn; it++) {
        int t = dir ? (Sn - 1 - it) : it;
        f32x4 acc = zero;

        // xw gate inputs for (b, hc) — independent of h; issue before the poll
        const u16* xp = &xw[((size_t)t * Bn + b) * G4 + (size_t)w * 16 + hc];
        float xg0 = bf2f(xp[0 * Hn]);
        float xg1 = bf2f(xp[1 * Hn]);
        float xg2 = bf2f(xp[2 * Hn]);
        float xg3 = bf2f(xp[3 * Hn]);

        if (it > 0) {
            int tprev = dir ? (t + 1) : (t - 1);
            const u16* base = &hbuf[((size_t)b * Sn + tprev) * Hn];
            const u16* p0 = base + (hc + 0) * 8;
            const u16* p1 = base + (hc + 16) * 8;
            const u16* p2 = base + (hc + 32) * 8;
            const u16* p3 = base + (hc + 48) * 8;
            f32x4 h0, h1, h2, h3;
            int tries = 0;
            for (;;) {
                // R8-proven sc1 sentinel poll: L1-bypassing; same-XCD dirty
                // L2 lines get serviced locally, else MALL backstop copy.
                asm volatile(
                    "global_load_dwordx4 %0, %4, off sc1\n\t"
                    "global_load_dwordx4 %1, %5, off sc1\n\t"
                    "global_load_dwordx4 %2, %6, off sc1\n\t"
                    "global_load_dwordx4 %3, %7, off sc1\n\t"
                    "s_waitcnt vmcnt(0)"
                    : "=&v"(h0), "=&v"(h1), "=&v"(h2), "=&v"(h3)
                    : "v"(p0), "v"(p1), "v"(p2), "v"(p3)
                    : "memory");
                if (!(badMask(h0) | badMask(h1) | badMask(h2) | badMask(h3))) break;
                if (++tries > (1 << 16)) break;   // fail-safe: never hang
            }
            *(f32x4*)&Hs[(b * 64 + ((hc + 0) ^ (b & 7))) * 8] = h0;
            *(f32x4*)&Hs[(b * 64 + ((hc + 16) ^ (b & 7))) * 8] = h1;
            *(f32x4*)&Hs[(b * 64 + ((hc + 32) ^ (b & 7))) * 8] = h2;
            *(f32x4*)&Hs[(b * 64 + ((hc + 48) ^ (b & 7))) * 8] = h3;
            __syncthreads();                              // sync #1

            f32x4 aa = zero, ab = zero;
            #pragma unroll
            for (int ks2 = 0; ks2 < 8; ks2++) {
                bf16x8 a0 = *(const bf16x8*)
                    &Hs[((mt * 16 + lm) * 64 + (((2 * ks2) * 4 + kq) ^ (lm & 7))) * 8];
                aa = __builtin_amdgcn_mfma_f32_16x16x32_bf16(a0, Bf[2 * ks2], aa, 0, 0, 0);
                bf16x8 a1 = *(const bf16x8*)
                    &Hs[((mt * 16 + lm) * 64 + (((2 * ks2 + 1) * 4 + kq) ^ (lm & 7))) * 8];
                ab = __builtin_amdgcn_mfma_f32_16x16x32_bf16(a1, Bf[2 * ks2 + 1], ab, 0, 0, 0);
            }
            acc = aa + ab;
        }

        #pragma unroll
        for (int reg = 0; reg < 4; reg++)
            Cp[(nt * 32 + mt * 16 + kq * 4 + reg) * 17 + lm] = acc[reg];
        __syncthreads();                                  // sync #2

        float g0 = Cp[(0 * 32 + b) * 17 + hc] + xg0;
        float g1 = Cp[(1 * 32 + b) * 17 + hc] + xg1;
        float g2 = Cp[(2 * 32 + b) * 17 + hc] + xg2;
        float g3 = Cp[(3 * 32 + b) * 17 + hc] + xg3;
        float i_ = sigmoidf_(g0);
        float f_ = sigmoidf_(g1);
        float gg = tanh_fast(g2);
        float o_ = sigmoidf_(g3);
        c_state = f_ * c_state + i_ * gg;
        float hv = o_ * tanh_fast(c_state);
        hout[tid] = f2bf(hv);
        __syncthreads();                                  // sync #3

        if (tid < 64) {
            int bq = lane >> 1, half = lane & 1;
            f32x4 hv8 = *(const f32x4*)&hout[lane * 8];
            u16* sp = &hbuf[((size_t)bq * Sn + t) * Hn + (size_t)w * 16 + half * 8];
            // dual store: XCD-local L2 copy (fast path) + MALL copy (backstop
            // + visibility under any routing). Same data, any order is fine.
            asm volatile(
                "global_store_dwordx4 %0, %1, off sc0\n\t"
                "global_store_dwordx4 %0, %1, off sc0 sc1"
                :: "v"(sp), "v"(hv8) : "memory");
        }
    }
}

// ---------------------------------------------------------------------------
// emis_crf: fused emission GEMM + exp + CRF accumulation.
// ---------------------------------------------------------------------------
__global__ __launch_bounds__(256) void emis_crf(
    const u16* __restrict__ hf, const u16* __restrict__ hb,
    const u16* __restrict__ wem_b, const float* __restrict__ bem,
    const float* __restrict__ expT, const int* __restrict__ labels,
    const int* __restrict__ lengths, float* __restrict__ e0,
    float* __restrict__ alphaAcc, float* __restrict__ realAcc)
{
    int mb = blockIdx.x;                 // 256 blocks
    int b = mb >> 3, t0 = (mb & 7) * 64; // rows mb*64.. are (b, t0..t0+64)

    __shared__ float eL[64][49];
    __shared__ float Ts[48 * 48];
    __shared__ float sred[4][48];
    __shared__ float rred[64];

    int tid = threadIdx.x;
    for (int i = tid; i < 48 * 48; i += 256) Ts[i] = expT[i];

    int wv = tid >> 6, lane = tid & 63;
    int lm = lane & 15, lkq = (lane >> 4) * 8;
    int row = mb * 64 + wv * 16;

    f32x4 zero = {0.f, 0.f, 0.f, 0.f};
    f32x4 acc[3] = {zero, zero, zero};
    for (int ks = 0; ks < 32; ks++) {
        int k = ks * 32 + lkq;
        const u16* hsrc = (ks < 16) ? &hf[(size_t)(row + lm) * Hn + k]
                                    : &hb[(size_t)(row + lm) * Hn + (k - 512)];
        bf16x8 a = *(const bf16x8*)hsrc;
        #pragma unroll
        for (int nt = 0; nt < 3; nt++) {
            bf16x8 bfr = *(const bf16x8*)&wem_b[(size_t)(nt * 16 + lm) * 1024 + k];
            acc[nt] = __builtin_amdgcn_mfma_f32_16x16x32_bf16(a, bfr, acc[nt], 0, 0, 0);
        }
    }
    #pragma unroll
    for (int nt = 0; nt < 3; nt++)
        #pragma unroll
        for (int reg = 0; reg < 4; reg++) {
            int rib = wv * 16 + (lane >> 4) * 4 + reg;   // row in block = t - t0
            int col = nt * 16 + lm;
            float v = expf(acc[nt][reg] + bem[col]);
            eL[rib][col] = v;
            if ((mb & 7) == 0 && rib == 0) e0[b * Ln + col] = v;   // t == 0
        }
    __syncthreads();

    int len = lengths[b];
    if (tid < 192) {
        int i = tid % 48, tg = tid / 48;   // 4 groups x 48 labels
        float sacc = 0.f;
        for (int p = tg * 16; p < tg * 16 + 16; p++) {
            int t = t0 + p;
            if (t >= 1 && t < len) {
                float m = -1e30f;
                for (int j = 0; j < 48; j++) m = fmaxf(m, Ts[i * 48 + j] + eL[p][j]);
                float s = 0.f;
                for (int j = 0; j < 48; j++) s += expf(Ts[i * 48 + j] + eL[p][j] - m);
                sacc += m + logf(s);
            }
        }
        sred[tg][i] = sacc;
    } else {
        int p = tid - 192;                  // 0..63
        int t = t0 + p;
        float r = 0.f;
        if (t < len) {
            int lab = labels[b * Sn + t];
            r = eL[p][lab];
            if (t >= 1) r += Ts[labels[b * Sn + t - 1] * 48 + lab];
        }
        rred[p] = r;
    }
    __syncthreads();
    if (tid < 48) {
        float s = sred[0][tid] + sred[1][tid] + sred[2][tid] + sred[3][tid];
        atomicAdd(&alphaAcc[b * Ln + tid], s);
    } else if (tid == 48) {
        float r = 0.f;
        for (int p = 0; p < 64; p++) r += rred[p];
        atomicAdd(&realAcc[b], r);
    }
}

__global__ __launch_bounds__(64) void finalize(
    const float* __restrict__ e0, const float* __restrict__ alphaAcc,
    const float* __restrict__ realAcc, float* __restrict__ out)
{
    int b = threadIdx.x;
    if (b >= Bn) return;
    float m = -1e30f;
    for (int i = 0; i < Ln; i++) {
        float a = e0[b * Ln + i] + alphaAcc[b * Ln + i];
        m = fmaxf(m, a);
    }
    float s = 0.f;
    for (int i = 0; i < Ln; i++) {
        float a = e0[b * Ln + i] + alphaAcc[b * Ln + i];
        s += expf(a - m);
    }
    out[b] = m + logf(s) - realAcc[b];
}

// ---------------------------------------------------------------------------
extern "C" void kernel_launch(void* const* d_in, const int* in_sizes, int n_in,
                              void* d_out, int out_size, void* d_ws, size_t ws_size,
                              hipStream_t stream)
{
    const int*   tokens = (const int*)d_in[0];
    const int*   length = (const int*)d_in[1];
    const int*   labels = (const int*)d_in[2];
    const float* embed  = (const float*)d_in[3];
    const float* wihf   = (const float*)d_in[4];
    const float* whhf   = (const float*)d_in[5];
    const float* bf     = (const float*)d_in[6];
    const float* wihb   = (const float*)d_in[7];
    const float* whhb   = (const float*)d_in[8];
    const float* bbv    = (const float*)d_in[9];
    const float* wem    = (const float*)d_in[10];
    const float* bem    = (const float*)d_in[11];
    const float* trans  = (const float*)d_in[12];
    float* out = (float*)d_out;

    char* p = (char*)d_ws;
    auto take = [&](size_t bytes) -> char* {
        char* q = p;
        p += (bytes + 255) & ~(size_t)255;
        return q;
    };
    u16* xw_f   = (u16*)take((size_t)Sn * Bn * G4 * 2);   // 64 MB
    u16* xw_b   = (u16*)take((size_t)Sn * Bn * G4 * 2);   // 64 MB
    u16* hf     = (u16*)take((size_t)Bn * Sn * Hn * 2);   // 16 MB, layout [b][t][k]
    u16* hb     = (u16*)take((size_t)Bn * Sn * Hn * 2);   // 16 MB, layout [b][t][k]
    u16* xbf    = (u16*)take((size_t)Bn * Sn * En * 2);   // 8 MB
    u16* wihf_b = (u16*)take((size_t)G4 * En * 2);
    u16* wihb_b = (u16*)take((size_t)G4 * En * 2);
    u16* whhf_b = (u16*)take((size_t)G4 * Hn * 2);
    u16* whhb_b = (u16*)take((size_t)G4 * Hn * 2);
    u16* wem_b  = (u16*)take((size_t)Ln * 2 * Hn * 2);
    float* expT     = (float*)take((size_t)Ln * Ln * 4);
    float* e0       = (float*)take((size_t)Bn * Ln * 4);
    float* alphaAcc = (float*)take((size_t)Bn * Ln * 4);
    float* realAcc  = (float*)take((size_t)Bn * 4);
    int* claimCnt   = (int*)take(16 * 4);
    int* teamCnt    = (int*)take(4);
    int* teamRole   = (int*)take(16 * 4);
    if ((size_t)(p - (char*)d_ws) > ws_size) return;

    prep_kernel<<<4096, 256, 0, stream>>>(tokens, embed, wihf, wihb, whhf, whhb, wem, trans,
                                          xbf, wihf_b, wihb_b, whhf_b, whhb_b, wem_b,
                                          expT, alphaAcc, realAcc,
                                          (unsigned*)hf, (unsigned*)hb,
                                          claimCnt, teamCnt, teamRole);

    dim3 g1(128, 16, 2);
    gemm_xw<<<g1, 256, 0, stream>>>(xbf, wihf_b, wihb_b, bf, bbv, xw_f, xw_b);

    lstm_rec<<<CLAIM_G, 512, 0, stream>>>(whhf_b, whhb_b, xw_f, xw_b, hf, hb,
                                          claimCnt, teamCnt, teamRole);

    emis_crf<<<256, 256, 0, stream>>>(hf, hb, wem_b, bem, expT, labels, length,
                                      e0, alphaAcc, realAcc);
    finalize<<<1, 64, 0, stream>>>(e0, alphaAcc, realAcc, out);
}

// Round 8
// 2614.444 us; speedup vs baseline: 273.4230x; 1.3112x over previous
//
#include <hip/hip_runtime.h>
#include <math.h>
#include <stdint.h>

// Problem constants
#define Bn 32
#define Sn 512
#define En 256
#define Hn 512
#define Ln 48
#define G4 2048        // 4*H
#define CLAIM_G 1024   // lstm_rec grid: WGs claim XCD-local team slots
#define NR 8           // rotating flag rounds (cold L1 line per round)
#define FLD 128        // dwords per flag round-line (512B stride)
#define SENT16 0x7FFFu // bf16 NaN — impossible for h = o*tanh(c), |h|<1

typedef unsigned short u16;
typedef __attribute__((ext_vector_type(8))) __bf16 bf16x8;
typedef __attribute__((ext_vector_type(4))) float f32x4;

__device__ inline float bf2f(u16 u) {
    return __uint_as_float(((unsigned)u) << 16);
}
__device__ inline u16 f2bf(float f) {
    unsigned u = __float_as_uint(f);
    unsigned r = (u + 0x7fffu + ((u >> 16) & 1u)) >> 16;  // RTNE
    return (u16)r;
}
__device__ inline float sigmoidf_(float x) { return 1.f / (1.f + expf(-x)); }
__device__ inline float tanh_fast(float x) { return 2.f / (1.f + expf(-2.f * x)) - 1.f; }

// any 16-bit field of the 4 dwords equals SENT16?
__device__ inline unsigned badMask(f32x4 v) {
    unsigned acc = 0;
    #pragma unroll
    for (int i = 0; i < 4; i++) {
        unsigned d = __float_as_uint(v[i]);
        unsigned x = d ^ 0x7FFF7FFFu;
        acc |= (x - 0x00010001u) & ~x & 0x80008000u;
    }
    return acc;
}

// ---------------------------------------------------------------------------
// prep: embed gather -> bf16 x, weight bf16 conversions, exp(T), zero accums,
// sentinel-fill h buffers, zero claim + flag state
// ---------------------------------------------------------------------------
__global__ __launch_bounds__(256) void prep_kernel(
    const int* __restrict__ tokens, const float* __restrict__ embed,
    const float* __restrict__ wihf, const float* __restrict__ wihb,
    const float* __restrict__ whhf, const float* __restrict__ whhb,
    const float* __restrict__ wem, const float* __restrict__ trans,
    u16* __restrict__ xbf, u16* __restrict__ wihf_b, u16* __restrict__ wihb_b,
    u16* __restrict__ whhf_b, u16* __restrict__ whhb_b, u16* __restrict__ wem_b,
    float* __restrict__ expT, float* __restrict__ alphaAcc,
    float* __restrict__ realAcc, unsigned* __restrict__ hf32,
    unsigned* __restrict__ hb32, int* __restrict__ claimCnt,
    int* __restrict__ teamCnt, int* __restrict__ teamRole,
    int* __restrict__ flags)
{
    size_t idx = (size_t)blockIdx.x * blockDim.x + threadIdx.x;
    size_t stride = (size_t)gridDim.x * blockDim.x;
    for (size_t i = idx; i < (size_t)Bn * Sn * En; i += stride) {
        size_t n = i >> 8; int ee = (int)(i & 255);
        int tok = tokens[n];
        xbf[i] = f2bf(embed[(size_t)tok * En + ee]);
    }
    for (size_t i = idx; i < (size_t)G4 * En; i += stride) {
        wihf_b[i] = f2bf(wihf[i]); wihb_b[i] = f2bf(wihb[i]);
    }
    for (size_t i = idx; i < (size_t)G4 * Hn; i += stride) {
        whhf_b[i] = f2bf(whhf[i]); whhb_b[i] = f2bf(whhb[i]);
    }
    for (size_t i = idx; i < (size_t)Ln * 2 * Hn; i += stride) wem_b[i] = f2bf(wem[i]);
    for (size_t i = idx; i < (size_t)Ln * Ln; i += stride) expT[i] = expf(trans[i]);
    for (size_t i = idx; i < (size_t)Bn * Ln; i += stride) alphaAcc[i] = 0.f;
    for (size_t i = idx; i < (size_t)Bn; i += stride) realAcc[i] = 0.f;
    for (size_t i = idx; i < 16; i += stride) { claimCnt[i] = 0; teamRole[i] = 0; }
    for (size_t i = idx; i < 1; i += stride) teamCnt[0] = 0;
    for (size_t i = idx; i < (size_t)2 * Sn * NR * FLD; i += stride) flags[i] = 0;
    const unsigned sp = (SENT16 << 16) | SENT16;
    for (size_t i = idx; i < (size_t)Bn * Sn * Hn / 2; i += stride) {
        hf32[i] = sp; hb32[i] = sp;
    }
}

// ---------------------------------------------------------------------------
// gemm_xw: xw[dir][t][b][g] = x(b,t) . w_ih[g] + bias[g], bf16 MFMA, fp32 acc
// ---------------------------------------------------------------------------
__global__ __launch_bounds__(256) void gemm_xw(
    const u16* __restrict__ xbf, const u16* __restrict__ wihf_b,
    const u16* __restrict__ wihb_b, const float* __restrict__ bias_f,
    const float* __restrict__ bias_b, u16* __restrict__ xw_f, u16* __restrict__ xw_b)
{
    int mb = blockIdx.x, nb = blockIdx.y, dir = blockIdx.z;
    const u16* wih = dir ? wihb_b : wihf_b;
    const float* bias = dir ? bias_b : bias_f;
    u16* xw = dir ? xw_b : xw_f;

    __shared__ u16 As[128 * 72];   // 128 rows x 64 k, pad 8
    __shared__ u16 Bs[128 * 72];

    int tid = threadIdx.x;
    int w = tid >> 6, lane = tid & 63;
    int lm = lane & 15, kq = lane >> 4;
    int Moff = (w & 1) * 64, Noff = (w >> 1) * 64;

    f32x4 zero = {0.f, 0.f, 0.f, 0.f};
    f32x4 acc[4][4];
    #pragma unroll
    for (int mi = 0; mi < 4; mi++)
        #pragma unroll
        for (int ni = 0; ni < 4; ni++) acc[mi][ni] = zero;

    for (int kc = 0; kc < 4; kc++) {
        #pragma unroll
        for (int it = 0; it < 4; it++) {
            int idx = tid + it * 256;
            int r = idx >> 3, pos = (idx & 7) * 8;
            *(bf16x8*)&As[r * 72 + pos] =
                *(const bf16x8*)&xbf[((size_t)(mb * 128 + r)) * En + kc * 64 + pos];
            *(bf16x8*)&Bs[r * 72 + pos] =
                *(const bf16x8*)&wih[((size_t)(nb * 128 + r)) * En + kc * 64 + pos];
        }
        __syncthreads();
        #pragma unroll
        for (int ks = 0; ks < 2; ks++) {
            int k = ks * 32 + kq * 8;
            bf16x8 af[4], bfr[4];
            #pragma unroll
            for (int mi = 0; mi < 4; mi++)
                af[mi] = *(const bf16x8*)&As[(Moff + mi * 16 + lm) * 72 + k];
            #pragma unroll
            for (int ni = 0; ni < 4; ni++)
                bfr[ni] = *(const bf16x8*)&Bs[(Noff + ni * 16 + lm) * 72 + k];
            #pragma unroll
            for (int mi = 0; mi < 4; mi++)
                #pragma unroll
                for (int ni = 0; ni < 4; ni++)
                    acc[mi][ni] = __builtin_amdgcn_mfma_f32_16x16x32_bf16(
                        af[mi], bfr[ni], acc[mi][ni], 0, 0, 0);
        }
        __syncthreads();
    }
    #pragma unroll
    for (int mi = 0; mi < 4; mi++)
        #pragma unroll
        for (int ni = 0; ni < 4; ni++)
            #pragma unroll
            for (int reg = 0; reg < 4; reg++) {
                int row = Moff + mi * 16 + kq * 4 + reg;
                int col = Noff + ni * 16 + lm;
                int n = mb * 128 + row;          // n = b*512 + t
                int g = nb * 128 + col;
                int t = n & 511, b = n >> 9;
                float v = acc[mi][ni][reg] + bias[g];
                xw[((size_t)t * Bn + b) * G4 + g] = f2bf(v);
            }
}

// ---------------------------------------------------------------------------
// lstm_rec (R16): 1024 plain WGs x 512 thr. R12's PROVEN XCD-local claiming.
// Exchange protocol built ONLY from HW-proven primitives:
//   producer wave 0: h slice store sc0 -> vmcnt(0) (L2 commit) -> readiness
//     flags written to NR=8 DISTINCT 512B-strided lines (lanes 0..7, sc0)
//     -> fire-and-forget sc1 h backstop copy (MALL; enables fallback).
//   consumer wave 0: poll round r reads flag LINE r — an address this CU's
//     L1 has NEVER touched -> forced L2 read -> sees same-XCD store (the
//     R12-proven cold-sc0 path). No repeated-address staleness (R13's bug),
//     no poll storm (R12's bug). Then all threads load the h row once (sc0,
//     cold) with sentinel check; bounded retries: 4x sc0 then sc1 (MALL
//     backstop copy exists). Flag poll bounded at NR rounds -> falls through
//     to data retry. Nothing can hang; worst case = R8-like sc1 polling.
// ---------------------------------------------------------------------------
__global__ __launch_bounds__(512) void lstm_rec(
    const u16* __restrict__ whhf_b, const u16* __restrict__ whhb_b,
    const u16* __restrict__ xw_f, const u16* __restrict__ xw_b,
    u16* __restrict__ hf, u16* __restrict__ hb,
    int* __restrict__ claimCnt, int* __restrict__ teamCnt,
    int* __restrict__ teamRole, int* __restrict__ flags)
{
    __shared__ int roleS[2];
    int tid = threadIdx.x;

    if (tid == 0) {
        unsigned xcdr;
        asm volatile("s_getreg_b32 %0, hwreg(HW_REG_XCC_ID)" : "=s"(xcdr));
        int myx = (int)(xcdr & 15);
        int slot = __hip_atomic_fetch_add(&claimCnt[myx], 1,
                                          __ATOMIC_ACQ_REL, __HIP_MEMORY_SCOPE_AGENT);
        int dir = -1;
        if (slot < 32) {
            if (slot == 31) {
                int ticket = __hip_atomic_fetch_add(teamCnt, 1,
                                  __ATOMIC_ACQ_REL, __HIP_MEMORY_SCOPE_AGENT);
                int role = (ticket == 0) ? 1 : (ticket == 1) ? 2 : -1;
                __hip_atomic_store(&teamRole[myx], role,
                                   __ATOMIC_RELEASE, __HIP_MEMORY_SCOPE_AGENT);
                dir = (role > 0) ? role - 1 : -1;
            } else {
                int r = 0, guard = 0;
                for (;;) {
                    r = __hip_atomic_load(&teamRole[myx],
                                          __ATOMIC_ACQUIRE, __HIP_MEMORY_SCOPE_AGENT);
                    if (r != 0) break;
                    if (++guard > (1 << 22)) break;   // failsafe
                    __builtin_amdgcn_s_sleep(2);
                }
                dir = (r > 0) ? r - 1 : -1;
            }
        }
        roleS[0] = dir;
        roleS[1] = slot & 31;
    }
    __syncthreads();
    int dir = roleS[0];
    int w = roleS[1];
    if (dir < 0) return;

    const u16* __restrict__ whh = dir ? whhb_b : whhf_b;
    const u16* __restrict__ xw  = dir ? xw_b  : xw_f;
    u16* __restrict__ hbuf = dir ? hb : hf;
    int* __restrict__ myflags = &flags[(size_t)dir * Sn * NR * FLD];

    __shared__ u16 Hs[32 * 512];        // h_{t-1} staged, XOR-swizzled chunks
    __shared__ float Cp[4 * 32 * 17];   // gate partials [gate][batch][hcol]
    __shared__ u16 hout[32 * 16];

    int wv = tid >> 6, lane = tid & 63;
    int lm = lane & 15, kq = lane >> 4;
    int mt = wv & 1, nt = wv >> 1;       // wave -> (batch-tile, gate)
    int b = tid >> 4, hc = tid & 15;     // gate-phase / staging role

    // B fragments (w_hh rows for gate nt, hidden cols w*16..+16) in registers
    bf16x8 Bf[16];
    {
        const u16* wrow = &whh[((size_t)nt * Hn + (size_t)w * 16 + lm) * Hn];
        #pragma unroll
        for (int ks = 0; ks < 16; ks++)
            Bf[ks] = *(const bf16x8*)&wrow[ks * 32 + kq * 8];
    }

    float c_state = 0.f;
    const f32x4 zero = {0.f, 0.f, 0.f, 0.f};

    for (int it = 0; it < Sn; it++) {
        int t = dir ? (Sn - 1 - it) : it;
        f32x4 acc = zero;

        // xw gate inputs for (b, hc) — independent of h; issue before the wait
        const u16* xp = &xw[((size_t)t * Bn + b) * G4 + (size_t)w * 16 + hc];
        float xg0 = bf2f(xp[0 * Hn]);
        float xg1 = bf2f(xp[1 * Hn]);
        float xg2 = bf2f(xp[2 * Hn]);
        float xg3 = bf2f(xp[3 * Hn]);

        if (it > 0) {
            int tprev = dir ? (t + 1) : (t - 1);
            // ---- readiness gate: wave 0, rotating COLD flag lines (sc0) ----
            if (wv == 0) {
                const int* fb = &myflags[(size_t)tprev * NR * FLD];
                for (int r = 0; r < NR; r++) {
                    int fv;
                    const int* fp = fb + r * FLD + (lane & 31);
                    asm volatile(
                        "global_load_dword %0, %1, off sc0\n\t"
                        "s_waitcnt vmcnt(0)"
                        : "=v"(fv) : "v"(fp) : "memory");
                    if (__ballot(fv != 0) == ~0ull) break;
                    __builtin_amdgcn_s_sleep(1);
                }
            }
            __syncthreads();                          // sync #0: gate passed
            // ---- single-shot data load (sc0 cold; XCD-local L2 serves) ----
            const u16* base = &hbuf[((size_t)b * Sn + tprev) * Hn];
            const u16* p0 = base + (hc + 0) * 8;
            const u16* p1 = base + (hc + 16) * 8;
            const u16* p2 = base + (hc + 32) * 8;
            const u16* p3 = base + (hc + 48) * 8;
            f32x4 h0, h1, h2, h3;
            int tries = 0;
            for (;;) {
                if (tries < 4) {
                    asm volatile(
                        "global_load_dwordx4 %0, %4, off sc0\n\t"
                        "global_load_dwordx4 %1, %5, off sc0\n\t"
                        "global_load_dwordx4 %2, %6, off sc0\n\t"
                        "global_load_dwordx4 %3, %7, off sc0\n\t"
                        "s_waitcnt vmcnt(0)"
                        : "=&v"(h0), "=&v"(h1), "=&v"(h2), "=&v"(h3)
                        : "v"(p0), "v"(p1), "v"(p2), "v"(p3)
                        : "memory");
                } else {
                    // escalation: MALL (backstop sc1 copy exists)
                    asm volatile(
                        "global_load_dwordx4 %0, %4, off sc1\n\t"
                        "global_load_dwordx4 %1, %5, off sc1\n\t"
                        "global_load_dwordx4 %2, %6, off sc1\n\t"
                        "global_load_dwordx4 %3, %7, off sc1\n\t"
                        "s_waitcnt vmcnt(0)"
                        : "=&v"(h0), "=&v"(h1), "=&v"(h2), "=&v"(h3)
                        : "v"(p0), "v"(p1), "v"(p2), "v"(p3)
                        : "memory");
                }
                if (!(badMask(h0) | badMask(h1) | badMask(h2) | badMask(h3))) break;
                if (++tries > (1 << 16)) break;   // fail-safe: never hang
            }
            *(f32x4*)&Hs[(b * 64 + ((hc + 0) ^ (b & 7))) * 8] = h0;
            *(f32x4*)&Hs[(b * 64 + ((hc + 16) ^ (b & 7))) * 8] = h1;
            *(f32x4*)&Hs[(b * 64 + ((hc + 32) ^ (b & 7))) * 8] = h2;
            *(f32x4*)&Hs[(b * 64 + ((hc + 48) ^ (b & 7))) * 8] = h3;
            __syncthreads();                              // sync #1

            f32x4 aa = zero, ab = zero;
            #pragma unroll
            for (int ks2 = 0; ks2 < 8; ks2++) {
                bf16x8 a0 = *(const bf16x8*)
                    &Hs[((mt * 16 + lm) * 64 + (((2 * ks2) * 4 + kq) ^ (lm & 7))) * 8];
                aa = __builtin_amdgcn_mfma_f32_16x16x32_bf16(a0, Bf[2 * ks2], aa, 0, 0, 0);
                bf16x8 a1 = *(const bf16x8*)
                    &Hs[((mt * 16 + lm) * 64 + (((2 * ks2 + 1) * 4 + kq) ^ (lm & 7))) * 8];
                ab = __builtin_amdgcn_mfma_f32_16x16x32_bf16(a1, Bf[2 * ks2 + 1], ab, 0, 0, 0);
            }
            acc = aa + ab;
        }

        #pragma unroll
        for (int reg = 0; reg < 4; reg++)
            Cp[(nt * 32 + mt * 16 + kq * 4 + reg) * 17 + lm] = acc[reg];
        __syncthreads();                                  // sync #2

        float g0 = Cp[(0 * 32 + b) * 17 + hc] + xg0;
        float g1 = Cp[(1 * 32 + b) * 17 + hc] + xg1;
        float g2 = Cp[(2 * 32 + b) * 17 + hc] + xg2;
        float g3 = Cp[(3 * 32 + b) * 17 + hc] + xg3;
        float i_ = sigmoidf_(g0);
        float f_ = sigmoidf_(g1);
        float gg = tanh_fast(g2);
        float o_ = sigmoidf_(g3);
        c_state = f_ * c_state + i_ * gg;
        float hv = o_ * tanh_fast(c_state);
        hout[tid] = f2bf(hv);
        __syncthreads();                                  // sync #3

        if (tid < 64) {
            int bq = lane >> 1, half = lane & 1;
            f32x4 hv8 = *(const f32x4*)&hout[lane * 8];
            u16* sp = &hbuf[((size_t)bq * Sn + t) * Hn + (size_t)w * 16 + half * 8];
            // h slice into XCD-local L2, wait for L2 commit
            asm volatile(
                "global_store_dwordx4 %0, %1, off sc0\n\t"
                "s_waitcnt vmcnt(0)"
                :: "v"(sp), "v"(hv8) : "memory");
            // readiness: NR rotating flag lines (lane r stores line r's dword)
            if (lane < NR) {
                int one = 1;
                int* fp = &myflags[((size_t)t * NR + lane) * FLD + w];
                asm volatile("global_store_dword %0, %1, off sc0"
                             :: "v"(fp), "v"(one) : "memory");
            }
            // MALL backstop copy (fire-and-forget; enables sc1 fallback)
            asm volatile("global_store_dwordx4 %0, %1, off sc1"
                         :: "v"(sp), "v"(hv8) : "memory");
        }
    }
}

// ---------------------------------------------------------------------------
// emis_crf: fused emission GEMM + exp + CRF accumulation.
// ---------------------------------------------------------------------------
__global__ __launch_bounds__(256) void emis_crf(
    const u16* __restrict__ hf, const u16* __restrict__ hb,
    const u16* __restrict__ wem_b, const float* __restrict__ bem,
    const float* __restrict__ expT, const int* __restrict__ labels,
    const int* __restrict__ lengths, float* __restrict__ e0,
    float* __restrict__ alphaAcc, float* __restrict__ realAcc)
{
    int mb = blockIdx.x;                 // 256 blocks
    int b = mb >> 3, t0 = (mb & 7) * 64; // rows mb*64.. are (b, t0..t0+64)

    __shared__ float eL[64][49];
    __shared__ float Ts[48 * 48];
    __shared__ float sred[4][48];
    __shared__ float rred[64];

    int tid = threadIdx.x;
    for (int i = tid; i < 48 * 48; i += 256) Ts[i] = expT[i];

    int wv = tid >> 6, lane = tid & 63;
    int lm = lane & 15, lkq = (lane >> 4) * 8;
    int row = mb * 64 + wv * 16;

    f32x4 zero = {0.f, 0.f, 0.f, 0.f};
    f32x4 acc[3] = {zero, zero, zero};
    for (int ks = 0; ks < 32; ks++) {
        int k = ks * 32 + lkq;
        const u16* hsrc = (ks < 16) ? &hf[(size_t)(row + lm) * Hn + k]
                                    : &hb[(size_t)(row + lm) * Hn + (k - 512)];
        bf16x8 a = *(const bf16x8*)hsrc;
        #pragma unroll
        for (int nt = 0; nt < 3; nt++) {
            bf16x8 bfr = *(const bf16x8*)&wem_b[(size_t)(nt * 16 + lm) * 1024 + k];
            acc[nt] = __builtin_amdgcn_mfma_f32_16x16x32_bf16(a, bfr, acc[nt], 0, 0, 0);
        }
    }
    #pragma unroll
    for (int nt = 0; nt < 3; nt++)
        #pragma unroll
        for (int reg = 0; reg < 4; reg++) {
            int rib = wv * 16 + (lane >> 4) * 4 + reg;   // row in block = t - t0
            int col = nt * 16 + lm;
            float v = expf(acc[nt][reg] + bem[col]);
            eL[rib][col] = v;
            if ((mb & 7) == 0 && rib == 0) e0[b * Ln + col] = v;   // t == 0
        }
    __syncthreads();

    int len = lengths[b];
    if (tid < 192) {
        int i = tid % 48, tg = tid / 48;   // 4 groups x 48 labels
        float sacc = 0.f;
        for (int p = tg * 16; p < tg * 16 + 16; p++) {
            int t = t0 + p;
            if (t >= 1 && t < len) {
                float m = -1e30f;
                for (int j = 0; j < 48; j++) m = fmaxf(m, Ts[i * 48 + j] + eL[p][j]);
                float s = 0.f;
                for (int j = 0; j < 48; j++) s += expf(Ts[i * 48 + j] + eL[p][j] - m);
                sacc += m + logf(s);
            }
        }
        sred[tg][i] = sacc;
    } else {
        int p = tid - 192;                  // 0..63
        int t = t0 + p;
        float r = 0.f;
        if (t < len) {
            int lab = labels[b * Sn + t];
            r = eL[p][lab];
            if (t >= 1) r += Ts[labels[b * Sn + t - 1] * 48 + lab];
        }
        rred[p] = r;
    }
    __syncthreads();
    if (tid < 48) {
        float s = sred[0][tid] + sred[1][tid] + sred[2][tid] + sred[3][tid];
        atomicAdd(&alphaAcc[b * Ln + tid], s);
    } else if (tid == 48) {
        float r = 0.f;
        for (int p = 0; p < 64; p++) r += rred[p];
        atomicAdd(&realAcc[b], r);
    }
}

__global__ __launch_bounds__(64) void finalize(
    const float* __restrict__ e0, const float* __restrict__ alphaAcc,
    const float* __restrict__ realAcc, float* __restrict__ out)
{
    int b = threadIdx.x;
    if (b >= Bn) return;
    float m = -1e30f;
    for (int i = 0; i < Ln; i++) {
        float a = e0[b * Ln + i] + alphaAcc[b * Ln + i];
        m = fmaxf(m, a);
    }
    float s = 0.f;
    for (int i = 0; i < Ln; i++) {
        float a = e0[b * Ln + i] + alphaAcc[b * Ln + i];
        s += expf(a - m);
    }
    out[b] = m + logf(s) - realAcc[b];
}

// ---------------------------------------------------------------------------
extern "C" void kernel_launch(void* const* d_in, const int* in_sizes, int n_in,
                              void* d_out, int out_size, void* d_ws, size_t ws_size,
                              hipStream_t stream)
{
    const int*   tokens = (const int*)d_in[0];
    const int*   length = (const int*)d_in[1];
    const int*   labels = (const int*)d_in[2];
    const float* embed  = (const float*)d_in[3];
    const float* wihf   = (const float*)d_in[4];
    const float* whhf   = (const float*)d_in[5];
    const float* bf     = (const float*)d_in[6];
    const float* wihb   = (const float*)d_in[7];
    const float* whhb   = (const float*)d_in[8];
    const float* bbv    = (const float*)d_in[9];
    const float* wem    = (const float*)d_in[10];
    const float* bem    = (const float*)d_in[11];
    const float* trans  = (const float*)d_in[12];
    float* out = (float*)d_out;

    char* p = (char*)d_ws;
    auto take = [&](size_t bytes) -> char* {
        char* q = p;
        p += (bytes + 255) & ~(size_t)255;
        return q;
    };
    u16* xw_f   = (u16*)take((size_t)Sn * Bn * G4 * 2);   // 64 MB
    u16* xw_b   = (u16*)take((size_t)Sn * Bn * G4 * 2);   // 64 MB
    u16* hf     = (u16*)take((size_t)Bn * Sn * Hn * 2);   // 16 MB, layout [b][t][k]
    u16* hb     = (u16*)take((size_t)Bn * Sn * Hn * 2);   // 16 MB, layout [b][t][k]
    u16* xbf    = (u16*)take((size_t)Bn * Sn * En * 2);   // 8 MB
    u16* wihf_b = (u16*)take((size_t)G4 * En * 2);
    u16* wihb_b = (u16*)take((size_t)G4 * En * 2);
    u16* whhf_b = (u16*)take((size_t)G4 * Hn * 2);
    u16* whhb_b = (u16*)take((size_t)G4 * Hn * 2);
    u16* wem_b  = (u16*)take((size_t)Ln * 2 * Hn * 2);
    float* expT     = (float*)take((size_t)Ln * Ln * 4);
    float* e0       = (float*)take((size_t)Bn * Ln * 4);
    float* alphaAcc = (float*)take((size_t)Bn * Ln * 4);
    float* realAcc  = (float*)take((size_t)Bn * 4);
    int* claimCnt   = (int*)take(16 * 4);
    int* teamCnt    = (int*)take(4);
    int* teamRole   = (int*)take(16 * 4);
    int* flags      = (int*)take((size_t)2 * Sn * NR * FLD * 4);   // 4 MB
    if ((size_t)(p - (char*)d_ws) > ws_size) return;

    prep_kernel<<<4096, 256, 0, stream>>>(tokens, embed, wihf, wihb, whhf, whhb, wem, trans,
                                          xbf, wihf_b, wihb_b, whhf_b, whhb_b, wem_b,
                                          expT, alphaAcc, realAcc,
                                          (unsigned*)hf, (unsigned*)hb,
                                          claimCnt, teamCnt, teamRole, flags);

    dim3 g1(128, 16, 2);
    gemm_xw<<<g1, 256, 0, stream>>>(xbf, wihf_b, wihb_b, bf, bbv, xw_f, xw_b);

    lstm_rec<<<CLAIM_G, 512, 0, stream>>>(whhf_b, whhb_b, xw_f, xw_b, hf, hb,
                                          claimCnt, teamCnt, teamRole, flags);

    emis_crf<<<256, 256, 0, stream>>>(hf, hb, wem_b, bem, expT, labels, length,
                                      e0, alphaAcc, realAcc);
    finalize<<<1, 64, 0, stream>>>(e0, alphaAcc, realAcc, out);
}

// Round 9
// 1872.739 us; speedup vs baseline: 381.7130x; 1.3961x over previous
//
#include <hip/hip_runtime.h>
#include <math.h>
#include <stdint.h>

// Problem constants
#define Bn 32
#define Sn 512
#define En 256
#define Hn 512
#define Ln 48
#define G4 2048        // 4*H
#define CLAIM_G 1024   // lstm_rec grid: WGs claim XCD-local team slots
#define NR 16          // rotating flag lines (cold L1 line per round)
#define FLD 32         // dwords per flag line (128B stride)
#define SENT16 0x7FFFu // bf16 NaN — impossible for h = o*tanh(c), |h|<1

typedef unsigned short u16;
typedef __attribute__((ext_vector_type(8))) __bf16 bf16x8;
typedef __attribute__((ext_vector_type(4))) float f32x4;

__device__ inline float bf2f(u16 u) {
    return __uint_as_float(((unsigned)u) << 16);
}
__device__ inline u16 f2bf(float f) {
    unsigned u = __float_as_uint(f);
    unsigned r = (u + 0x7fffu + ((u >> 16) & 1u)) >> 16;  // RTNE
    return (u16)r;
}
__device__ inline float sigmoidf_(float x) { return 1.f / (1.f + expf(-x)); }
__device__ inline float tanh_fast(float x) { return 2.f / (1.f + expf(-2.f * x)) - 1.f; }

// any 16-bit field of the 4 dwords equals SENT16?
__device__ inline unsigned badMask(f32x4 v) {
    unsigned acc = 0;
    #pragma unroll
    for (int i = 0; i < 4; i++) {
        unsigned d = __float_as_uint(v[i]);
        unsigned x = d ^ 0x7FFF7FFFu;
        acc |= (x - 0x00010001u) & ~x & 0x80008000u;
    }
    return acc;
}

// ---------------------------------------------------------------------------
// prep: embed gather -> bf16 x, weight bf16 conversions, exp(T), zero accums,
// sentinel-fill h buffers, zero claim + flag state
// ---------------------------------------------------------------------------
__global__ __launch_bounds__(256) void prep_kernel(
    const int* __restrict__ tokens, const float* __restrict__ embed,
    const float* __restrict__ wihf, const float* __restrict__ wihb,
    const float* __restrict__ whhf, const float* __restrict__ whhb,
    const float* __restrict__ wem, const float* __restrict__ trans,
    u16* __restrict__ xbf, u16* __restrict__ wihf_b, u16* __restrict__ wihb_b,
    u16* __restrict__ whhf_b, u16* __restrict__ whhb_b, u16* __restrict__ wem_b,
    float* __restrict__ expT, float* __restrict__ alphaAcc,
    float* __restrict__ realAcc, unsigned* __restrict__ hf32,
    unsigned* __restrict__ hb32, int* __restrict__ claimCnt,
    int* __restrict__ teamCnt, int* __restrict__ teamRole,
    int* __restrict__ flags)
{
    size_t idx = (size_t)blockIdx.x * blockDim.x + threadIdx.x;
    size_t stride = (size_t)gridDim.x * blockDim.x;
    for (size_t i = idx; i < (size_t)Bn * Sn * En; i += stride) {
        size_t n = i >> 8; int ee = (int)(i & 255);
        int tok = tokens[n];
        xbf[i] = f2bf(embed[(size_t)tok * En + ee]);
    }
    for (size_t i = idx; i < (size_t)G4 * En; i += stride) {
        wihf_b[i] = f2bf(wihf[i]); wihb_b[i] = f2bf(wihb[i]);
    }
    for (size_t i = idx; i < (size_t)G4 * Hn; i += stride) {
        whhf_b[i] = f2bf(whhf[i]); whhb_b[i] = f2bf(whhb[i]);
    }
    for (size_t i = idx; i < (size_t)Ln * 2 * Hn; i += stride) wem_b[i] = f2bf(wem[i]);
    for (size_t i = idx; i < (size_t)Ln * Ln; i += stride) expT[i] = expf(trans[i]);
    for (size_t i = idx; i < (size_t)Bn * Ln; i += stride) alphaAcc[i] = 0.f;
    for (size_t i = idx; i < (size_t)Bn; i += stride) realAcc[i] = 0.f;
    for (size_t i = idx; i < 16; i += stride) { claimCnt[i] = 0; teamRole[i] = 0; }
    for (size_t i = idx; i < 1; i += stride) teamCnt[0] = 0;
    for (size_t i = idx; i < (size_t)2 * Sn * NR * FLD; i += stride) flags[i] = 0;
    const unsigned sp = (SENT16 << 16) | SENT16;
    for (size_t i = idx; i < (size_t)Bn * Sn * Hn / 2; i += stride) {
        hf32[i] = sp; hb32[i] = sp;
    }
}

// ---------------------------------------------------------------------------
// gemm_xw: xw[dir][t][b][g] = x(b,t) . w_ih[g] + bias[g], bf16 MFMA, fp32 acc
// ---------------------------------------------------------------------------
__global__ __launch_bounds__(256) void gemm_xw(
    const u16* __restrict__ xbf, const u16* __restrict__ wihf_b,
    const u16* __restrict__ wihb_b, const float* __restrict__ bias_f,
    const float* __restrict__ bias_b, u16* __restrict__ xw_f, u16* __restrict__ xw_b)
{
    int mb = blockIdx.x, nb = blockIdx.y, dir = blockIdx.z;
    const u16* wih = dir ? wihb_b : wihf_b;
    const float* bias = dir ? bias_b : bias_f;
    u16* xw = dir ? xw_b : xw_f;

    __shared__ u16 As[128 * 72];   // 128 rows x 64 k, pad 8
    __shared__ u16 Bs[128 * 72];

    int tid = threadIdx.x;
    int w = tid >> 6, lane = tid & 63;
    int lm = lane & 15, kq = lane >> 4;
    int Moff = (w & 1) * 64, Noff = (w >> 1) * 64;

    f32x4 zero = {0.f, 0.f, 0.f, 0.f};
    f32x4 acc[4][4];
    #pragma unroll
    for (int mi = 0; mi < 4; mi++)
        #pragma unroll
        for (int ni = 0; ni < 4; ni++) acc[mi][ni] = zero;

    for (int kc = 0; kc < 4; kc++) {
        #pragma unroll
        for (int it = 0; it < 4; it++) {
            int idx = tid + it * 256;
            int r = idx >> 3, pos = (idx & 7) * 8;
            *(bf16x8*)&As[r * 72 + pos] =
                *(const bf16x8*)&xbf[((size_t)(mb * 128 + r)) * En + kc * 64 + pos];
            *(bf16x8*)&Bs[r * 72 + pos] =
                *(const bf16x8*)&wih[((size_t)(nb * 128 + r)) * En + kc * 64 + pos];
        }
        __syncthreads();
        #pragma unroll
        for (int ks = 0; ks < 2; ks++) {
            int k = ks * 32 + kq * 8;
            bf16x8 af[4], bfr[4];
            #pragma unroll
            for (int mi = 0; mi < 4; mi++)
                af[mi] = *(const bf16x8*)&As[(Moff + mi * 16 + lm) * 72 + k];
            #pragma unroll
            for (int ni = 0; ni < 4; ni++)
                bfr[ni] = *(const bf16x8*)&Bs[(Noff + ni * 16 + lm) * 72 + k];
            #pragma unroll
            for (int mi = 0; mi < 4; mi++)
                #pragma unroll
                for (int ni = 0; ni < 4; ni++)
                    acc[mi][ni] = __builtin_amdgcn_mfma_f32_16x16x32_bf16(
                        af[mi], bfr[ni], acc[mi][ni], 0, 0, 0);
        }
        __syncthreads();
    }
    #pragma unroll
    for (int mi = 0; mi < 4; mi++)
        #pragma unroll
        for (int ni = 0; ni < 4; ni++)
            #pragma unroll
            for (int reg = 0; reg < 4; reg++) {
                int row = Moff + mi * 16 + kq * 4 + reg;
                int col = Noff + ni * 16 + lm;
                int n = mb * 128 + row;          // n = b*512 + t
                int g = nb * 128 + col;
                int t = n & 511, b = n >> 9;
                float v = acc[mi][ni][reg] + bias[g];
                xw[((size_t)t * Bn + b) * G4 + g] = f2bf(v);
            }
}

// ---------------------------------------------------------------------------
// lstm_rec (R17): 1024 plain WGs x 512 thr. R12's PROVEN XCD-local claiming.
// PURE-sc0 exchange — no MALL (sc1) operation anywhere in the loop. R16's
// residual 2.5us/step was the fire-and-forget sc1 backstop store: the next
// iteration's vmcnt(0) drained it to MALL on the critical path. Removed.
//   producer wave 0: h store sc0 -> vmcnt(0) (L2 ack) -> flag stores sc0 to
//     NR=16 distinct 128B-strided lines. Nothing else.
//   consumer wave 0: rotating COLD-line flag poll (forced L2 read each of
//     the first NR rounds — the R12-proven cold-sc0 visibility path), then
//     cycling rounds with sleep; budget 512 rounds. Then all threads load
//     the h row once (sc0 cold). Fallback (never-path; gate pass implies
//     data in L2): bounded sc0 re-reads + sleep, progress via L1 eviction
//     (R12-proven). Inter-kernel visibility of sc0-only stores: proven R13.
// All loops bounded; worst case slow-but-correct, no hang, no wrong data.
// ---------------------------------------------------------------------------
__global__ __launch_bounds__(512) void lstm_rec(
    const u16* __restrict__ whhf_b, const u16* __restrict__ whhb_b,
    const u16* __restrict__ xw_f, const u16* __restrict__ xw_b,
    u16* __restrict__ hf, u16* __restrict__ hb,
    int* __restrict__ claimCnt, int* __restrict__ teamCnt,
    int* __restrict__ teamRole, int* __restrict__ flags)
{
    __shared__ int roleS[2];
    int tid = threadIdx.x;

    if (tid == 0) {
        unsigned xcdr;
        asm volatile("s_getreg_b32 %0, hwreg(HW_REG_XCC_ID)" : "=s"(xcdr));
        int myx = (int)(xcdr & 15);
        int slot = __hip_atomic_fetch_add(&claimCnt[myx], 1,
                                          __ATOMIC_ACQ_REL, __HIP_MEMORY_SCOPE_AGENT);
        int dir = -1;
        if (slot < 32) {
            if (slot == 31) {
                int ticket = __hip_atomic_fetch_add(teamCnt, 1,
                                  __ATOMIC_ACQ_REL, __HIP_MEMORY_SCOPE_AGENT);
                int role = (ticket == 0) ? 1 : (ticket == 1) ? 2 : -1;
                __hip_atomic_store(&teamRole[myx], role,
                                   __ATOMIC_RELEASE, __HIP_MEMORY_SCOPE_AGENT);
                dir = (role > 0) ? role - 1 : -1;
            } else {
                int r = 0, guard = 0;
                for (;;) {
                    r = __hip_atomic_load(&teamRole[myx],
                                          __ATOMIC_ACQUIRE, __HIP_MEMORY_SCOPE_AGENT);
                    if (r != 0) break;
                    if (++guard > (1 << 22)) break;   // failsafe
                    __builtin_amdgcn_s_sleep(2);
                }
                dir = (r > 0) ? r - 1 : -1;
            }
        }
        roleS[0] = dir;
        roleS[1] = slot & 31;
    }
    __syncthreads();
    int dir = roleS[0];
    int w = roleS[1];
    if (dir < 0) return;

    const u16* __restrict__ whh = dir ? whhb_b : whhf_b;
    const u16* __restrict__ xw  = dir ? xw_b  : xw_f;
    u16* __restrict__ hbuf = dir ? hb : hf;
    int* __restrict__ myflags = &flags[(size_t)dir * Sn * NR * FLD];

    __shared__ u16 Hs[32 * 512];        // h_{t-1} staged, XOR-swizzled chunks
    __shared__ float Cp[4 * 32 * 17];   // gate partials [gate][batch][hcol]
    __shared__ u16 hout[32 * 16];

    int wv = tid >> 6, lane = tid & 63;
    int lm = lane & 15, kq = lane >> 4;
    int mt = wv & 1, nt = wv >> 1;       // wave -> (batch-tile, gate)
    int b = tid >> 4, hc = tid & 15;     // gate-phase / staging role

    // B fragments (w_hh rows for gate nt, hidden cols w*16..+16) in registers
    bf16x8 Bf[16];
    {
        const u16* wrow = &whh[((size_t)nt * Hn + (size_t)w * 16 + lm) * Hn];
        #pragma unroll
        for (int ks = 0; ks < 16; ks++)
            Bf[ks] = *(const bf16x8*)&wrow[ks * 32 + kq * 8];
    }

    float c_state = 0.f;
    const f32x4 zero = {0.f, 0.f, 0.f, 0.f};

    for (int it = 0; it < Sn; it++) {
        int t = dir ? (Sn - 1 - it) : it;
        f32x4 acc = zero;

        // xw gate inputs for (b, hc) — independent of h; issue before the wait.
        // Waves 1-7: fully hidden behind their sync#0 wait. Wave 0: drained by
        // gate round 0's vmcnt(0), overlapping the inherent flag-visibility
        // delay (~600cy) — near-free.
        const u16* xp = &xw[((size_t)t * Bn + b) * G4 + (size_t)w * 16 + hc];
        float xg0 = bf2f(xp[0 * Hn]);
        float xg1 = bf2f(xp[1 * Hn]);
        float xg2 = bf2f(xp[2 * Hn]);
        float xg3 = bf2f(xp[3 * Hn]);

        if (it > 0) {
            int tprev = dir ? (t + 1) : (t - 1);
            // ---- readiness gate: wave 0, rotating COLD flag lines (sc0) ----
            if (wv == 0) {
                const int* fb = &myflags[(size_t)tprev * NR * FLD];
                for (int r = 0; r < 512; r++) {
                    int fv;
                    const int* fp = fb + (r & (NR - 1)) * FLD + (lane & 31);
                    asm volatile(
                        "global_load_dword %0, %1, off sc0\n\t"
                        "s_waitcnt vmcnt(0)"
                        : "=v"(fv) : "v"(fp) : "memory");
                    if (__ballot(fv != 0) == ~0ull) break;
                    if (r >= NR) __builtin_amdgcn_s_sleep(2);
                }
            }
            __syncthreads();                          // sync #0: gate passed
            // ---- single-shot data load (sc0 cold; XCD-local L2 serves) ----
            const u16* base = &hbuf[((size_t)b * Sn + tprev) * Hn];
            const u16* p0 = base + (hc + 0) * 8;
            const u16* p1 = base + (hc + 16) * 8;
            const u16* p2 = base + (hc + 32) * 8;
            const u16* p3 = base + (hc + 48) * 8;
            f32x4 h0, h1, h2, h3;
            asm volatile(
                "global_load_dwordx4 %0, %4, off sc0\n\t"
                "global_load_dwordx4 %1, %5, off sc0\n\t"
                "global_load_dwordx4 %2, %6, off sc0\n\t"
                "global_load_dwordx4 %3, %7, off sc0\n\t"
                "s_waitcnt vmcnt(0)"
                : "=&v"(h0), "=&v"(h1), "=&v"(h2), "=&v"(h3)
                : "v"(p0), "v"(p1), "v"(p2), "v"(p3)
                : "memory");
            // ---- never-path fallback: bounded sc0 re-reads (L1 eviction) ---
            {
                unsigned bad = badMask(h0) | badMask(h1) | badMask(h2) | badMask(h3);
                int guard = 0;
                while (bad && ++guard < 2048) {
                    __builtin_amdgcn_s_sleep(8);
                    asm volatile(
                        "global_load_dwordx4 %0, %4, off sc0\n\t"
                        "global_load_dwordx4 %1, %5, off sc0\n\t"
                        "global_load_dwordx4 %2, %6, off sc0\n\t"
                        "global_load_dwordx4 %3, %7, off sc0\n\t"
                        "s_waitcnt vmcnt(0)"
                        : "=&v"(h0), "=&v"(h1), "=&v"(h2), "=&v"(h3)
                        : "v"(p0), "v"(p1), "v"(p2), "v"(p3)
                        : "memory");
                    bad = badMask(h0) | badMask(h1) | badMask(h2) | badMask(h3);
                }
            }
            *(f32x4*)&Hs[(b * 64 + ((hc + 0) ^ (b & 7))) * 8] = h0;
            *(f32x4*)&Hs[(b * 64 + ((hc + 16) ^ (b & 7))) * 8] = h1;
            *(f32x4*)&Hs[(b * 64 + ((hc + 32) ^ (b & 7))) * 8] = h2;
            *(f32x4*)&Hs[(b * 64 + ((hc + 48) ^ (b & 7))) * 8] = h3;
            __syncthreads();                              // sync #1

            f32x4 aa = zero, ab = zero;
            #pragma unroll
            for (int ks2 = 0; ks2 < 8; ks2++) {
                bf16x8 a0 = *(const bf16x8*)
                    &Hs[((mt * 16 + lm) * 64 + (((2 * ks2) * 4 + kq) ^ (lm & 7))) * 8];
                aa = __builtin_amdgcn_mfma_f32_16x16x32_bf16(a0, Bf[2 * ks2], aa, 0, 0, 0);
                bf16x8 a1 = *(const bf16x8*)
                    &Hs[((mt * 16 + lm) * 64 + (((2 * ks2 + 1) * 4 + kq) ^ (lm & 7))) * 8];
                ab = __builtin_amdgcn_mfma_f32_16x16x32_bf16(a1, Bf[2 * ks2 + 1], ab, 0, 0, 0);
            }
            acc = aa + ab;
        }

        #pragma unroll
        for (int reg = 0; reg < 4; reg++)
            Cp[(nt * 32 + mt * 16 + kq * 4 + reg) * 17 + lm] = acc[reg];
        __syncthreads();                                  // sync #2

        float g0 = Cp[(0 * 32 + b) * 17 + hc] + xg0;
        float g1 = Cp[(1 * 32 + b) * 17 + hc] + xg1;
        float g2 = Cp[(2 * 32 + b) * 17 + hc] + xg2;
        float g3 = Cp[(3 * 32 + b) * 17 + hc] + xg3;
        float i_ = sigmoidf_(g0);
        float f_ = sigmoidf_(g1);
        float gg = tanh_fast(g2);
        float o_ = sigmoidf_(g3);
        c_state = f_ * c_state + i_ * gg;
        float hv = o_ * tanh_fast(c_state);
        hout[tid] = f2bf(hv);
        __syncthreads();                                  // sync #3

        if (tid < 64) {
            int bq = lane >> 1, half = lane & 1;
            f32x4 hv8 = *(const f32x4*)&hout[lane * 8];
            u16* sp = &hbuf[((size_t)bq * Sn + t) * Hn + (size_t)w * 16 + half * 8];
            // h slice into XCD-local L2, wait for L2 commit (ordering for flag)
            asm volatile(
                "global_store_dwordx4 %0, %1, off sc0\n\t"
                "s_waitcnt vmcnt(0)"
                :: "v"(sp), "v"(hv8) : "memory");
            // readiness: NR rotating flag lines (lane r stores line r, dword w)
            if (lane < NR) {
                int one = 1;
                int* fp = &myflags[((size_t)t * NR + lane) * FLD + w];
                asm volatile("global_store_dword %0, %1, off sc0"
                             :: "v"(fp), "v"(one) : "memory");
            }
            // NO sc1 backstop — a MALL store here re-enters the critical path
            // via the next iteration's vmcnt(0) drain (R16's 2.5us residual).
        }
    }
}

// ---------------------------------------------------------------------------
// emis_crf: fused emission GEMM + exp + CRF accumulation.
// ---------------------------------------------------------------------------
__global__ __launch_bounds__(256) void emis_crf(
    const u16* __restrict__ hf, const u16* __restrict__ hb,
    const u16* __restrict__ wem_b, const float* __restrict__ bem,
    const float* __restrict__ expT, const int* __restrict__ labels,
    const int* __restrict__ lengths, float* __restrict__ e0,
    float* __restrict__ alphaAcc, float* __restrict__ realAcc)
{
    int mb = blockIdx.x;                 // 256 blocks
    int b = mb >> 3, t0 = (mb & 7) * 64; // rows mb*64.. are (b, t0..t0+64)

    __shared__ float eL[64][49];
    __shared__ float Ts[48 * 48];
    __shared__ float sred[4][48];
    __shared__ float rred[64];

    int tid = threadIdx.x;
    for (int i = tid; i < 48 * 48; i += 256) Ts[i] = expT[i];

    int wv = tid >> 6, lane = tid & 63;
    int lm = lane & 15, lkq = (lane >> 4) * 8;
    int row = mb * 64 + wv * 16;

    f32x4 zero = {0.f, 0.f, 0.f, 0.f};
    f32x4 acc[3] = {zero, zero, zero};
    for (int ks = 0; ks < 32; ks++) {
        int k = ks * 32 + lkq;
        const u16* hsrc = (ks < 16) ? &hf[(size_t)(row + lm) * Hn + k]
                                    : &hb[(size_t)(row + lm) * Hn + (k - 512)];
        bf16x8 a = *(const bf16x8*)hsrc;
        #pragma unroll
        for (int nt = 0; nt < 3; nt++) {
            bf16x8 bfr = *(const bf16x8*)&wem_b[(size_t)(nt * 16 + lm) * 1024 + k];
            acc[nt] = __builtin_amdgcn_mfma_f32_16x16x32_bf16(a, bfr, acc[nt], 0, 0, 0);
        }
    }
    #pragma unroll
    for (int nt = 0; nt < 3; nt++)
        #pragma unroll
        for (int reg = 0; reg < 4; reg++) {
            int rib = wv * 16 + (lane >> 4) * 4 + reg;   // row in block = t - t0
            int col = nt * 16 + lm;
            float v = expf(acc[nt][reg] + bem[col]);
            eL[rib][col] = v;
            if ((mb & 7) == 0 && rib == 0) e0[b * Ln + col] = v;   // t == 0
        }
    __syncthreads();

    int len = lengths[b];
    if (tid < 192) {
        int i = tid % 48, tg = tid / 48;   // 4 groups x 48 labels
        float sacc = 0.f;
        for (int p = tg * 16; p < tg * 16 + 16; p++) {
            int t = t0 + p;
            if (t >= 1 && t < len) {
                float m = -1e30f;
                for (int j = 0; j < 48; j++) m = fmaxf(m, Ts[i * 48 + j] + eL[p][j]);
                float s = 0.f;
                for (int j = 0; j < 48; j++) s += expf(Ts[i * 48 + j] + eL[p][j] - m);
                sacc += m + logf(s);
            }
        }
        sred[tg][i] = sacc;
    } else {
        int p = tid - 192;                  // 0..63
        int t = t0 + p;
        float r = 0.f;
        if (t < len) {
            int lab = labels[b * Sn + t];
            r = eL[p][lab];
            if (t >= 1) r += Ts[labels[b * Sn + t - 1] * 48 + lab];
        }
        rred[p] = r;
    }
    __syncthreads();
    if (tid < 48) {
        float s = sred[0][tid] + sred[1][tid] + sred[2][tid] + sred[3][tid];
        atomicAdd(&alphaAcc[b * Ln + tid], s);
    } else if (tid == 48) {
        float r = 0.f;
        for (int p = 0; p < 64; p++) r += rred[p];
        atomicAdd(&realAcc[b], r);
    }
}

__global__ __launch_bounds__(64) void finalize(
    const float* __restrict__ e0, const float* __restrict__ alphaAcc,
    const float* __restrict__ realAcc, float* __restrict__ out)
{
    int b = threadIdx.x;
    if (b >= Bn) return;
    float m = -1e30f;
    for (int i = 0; i < Ln; i++) {
        float a = e0[b * Ln + i] + alphaAcc[b * Ln + i];
        m = fmaxf(m, a);
    }
    float s = 0.f;
    for (int i = 0; i < Ln; i++) {
        float a = e0[b * Ln + i] + alphaAcc[b * Ln + i];
        s += expf(a - m);
    }
    out[b] = m + logf(s) - realAcc[b];
}

// ---------------------------------------------------------------------------
extern "C" void kernel_launch(void* const* d_in, const int* in_sizes, int n_in,
                              void* d_out, int out_size, void* d_ws, size_t ws_size,
                              hipStream_t stream)
{
    const int*   tokens = (const int*)d_in[0];
    const int*   length = (const int*)d_in[1];
    const int*   labels = (const int*)d_in[2];
    const float* embed  = (const float*)d_in[3];
    const float* wihf   = (const float*)d_in[4];
    const float* whhf   = (const float*)d_in[5];
    const float* bf     = (const float*)d_in[6];
    const float* wihb   = (const float*)d_in[7];
    const float* whhb   = (const float*)d_in[8];
    const float* bbv    = (const float*)d_in[9];
    const float* wem    = (const float*)d_in[10];
    const float* bem    = (const float*)d_in[11];
    const float* trans  = (const float*)d_in[12];
    float* out = (float*)d_out;

    char* p = (char*)d_ws;
    auto take = [&](size_t bytes) -> char* {
        char* q = p;
        p += (bytes + 255) & ~(size_t)255;
        return q;
    };
    u16* xw_f   = (u16*)take((size_t)Sn * Bn * G4 * 2);   // 64 MB
    u16* xw_b   = (u16*)take((size_t)Sn * Bn * G4 * 2);   // 64 MB
    u16* hf     = (u16*)take((size_t)Bn * Sn * Hn * 2);   // 16 MB, layout [b][t][k]
    u16* hb     = (u16*)take((size_t)Bn * Sn * Hn * 2);   // 16 MB, layout [b][t][k]
    u16* xbf    = (u16*)take((size_t)Bn * Sn * En * 2);   // 8 MB
    u16* wihf_b = (u16*)take((size_t)G4 * En * 2);
    u16* wihb_b = (u16*)take((size_t)G4 * En * 2);
    u16* whhf_b = (u16*)take((size_t)G4 * Hn * 2);
    u16* whhb_b = (u16*)take((size_t)G4 * Hn * 2);
    u16* wem_b  = (u16*)take((size_t)Ln * 2 * Hn * 2);
    float* expT     = (float*)take((size_t)Ln * Ln * 4);
    float* e0       = (float*)take((size_t)Bn * Ln * 4);
    float* alphaAcc = (float*)take((size_t)Bn * Ln * 4);
    float* realAcc  = (float*)take((size_t)Bn * 4);
    int* claimCnt   = (int*)take(16 * 4);
    int* teamCnt    = (int*)take(4);
    int* teamRole   = (int*)take(16 * 4);
    int* flags      = (int*)take((size_t)2 * Sn * NR * FLD * 4);   // 2 MB
    if ((size_t)(p - (char*)d_ws) > ws_size) return;

    prep_kernel<<<4096, 256, 0, stream>>>(tokens, embed, wihf, wihb, whhf, whhb, wem, trans,
                                          xbf, wihf_b, wihb_b, whhf_b, whhb_b, wem_b,
                                          expT, alphaAcc, realAcc,
                                          (unsigned*)hf, (unsigned*)hb,
                                          claimCnt, teamCnt, teamRole, flags);

    dim3 g1(128, 16, 2);
    gemm_xw<<<g1, 256, 0, stream>>>(xbf, wihf_b, wihb_b, bf, bbv, xw_f, xw_b);

    lstm_rec<<<CLAIM_G, 512, 0, stream>>>(whhf_b, whhb_b, xw_f, xw_b, hf, hb,
                                          claimCnt, teamCnt, teamRole, flags);

    emis_crf<<<256, 256, 0, stream>>>(hf, hb, wem_b, bem, expT, labels, length,
                                      e0, alphaAcc, realAcc);
    finalize<<<1, 64, 0, stream>>>(e0, alphaAcc, realAcc, out);
}